// Round 4
// baseline (20537.474 us; speedup 1.0000x reference)
//
#include <hip/hip_runtime.h>
#include <hip/hip_bf16.h>

#define B_ 4096
#define H_ 256
#define I_ 32
#define TM 16
#define PAD 260   // LDS row stride (floats): 16B-aligned, 260%32=4 rotates banks per row

// Static inter-level hidden buffer: 32 slots of (B x H) fp32 = 128 MiB.
// In-place binary-tree contraction: level-d node j occupies slot j*2^(5-d).
__device__ float g_hid[(size_t)32 * B_ * H_];

__device__ __forceinline__ float sigf(float x){ return 1.0f/(1.0f+__expf(-x)); }

// Block-cooperative GEMM: out tile = X(16 x K) @ W(256 x K)^T, thread owns 4x4 micro-tile.
// cg = tid&63 -> cols n0=4*cg ; rg = tid>>6 -> rows m0=4*rg (rows wave-exclusive: wave == rg).
// W staged to LDS in k-chunks of 16 (k-major, padded).
template<int K, int XS>
__device__ __forceinline__ void gemm_tile(const float* __restrict__ W,
                                          const float* __restrict__ X,
                                          float (*Wb)[PAD],
                                          int tid, int m0, int n0,
                                          float acc[4][4])
{
#pragma unroll
  for (int i=0;i<4;++i)
#pragma unroll
    for (int j=0;j<4;++j) acc[i][j]=0.f;

  for (int k0=0;k0<K;k0+=16){
    __syncthreads();                    // orders prior LDS writes (incl. X updates) before Wb restage
#pragma unroll
    for (int i=0;i<4;++i){
      int idx = i*256+tid;              // 1024 float4s = 256 rows x 16 k
      int n  = idx>>2;
      int j4 = idx&3;
      float4 v = *(const float4*)(W + n*K + k0 + 4*j4);
      Wb[4*j4+0][n]=v.x; Wb[4*j4+1][n]=v.y; Wb[4*j4+2][n]=v.z; Wb[4*j4+3][n]=v.w;
    }
    __syncthreads();
#pragma unroll
    for (int ku=0;ku<4;++ku){
      float4 xv[4], wv[4];
#pragma unroll
      for (int mi=0;mi<4;++mi) xv[mi]=*(const float4*)(X + (m0+mi)*XS + k0 + 4*ku);  // wave-broadcast
#pragma unroll
      for (int kk=0;kk<4;++kk) wv[kk]=*(const float4*)(&Wb[4*ku+kk][n0]);
#pragma unroll
      for (int mi=0;mi<4;++mi){
        const float* xp = (const float*)&xv[mi];
#pragma unroll
        for (int kk=0;kk<4;++kk){
          acc[mi][0] += xp[kk]*wv[kk].x;
          acc[mi][1] += xp[kk]*wv[kk].y;
          acc[mi][2] += xp[kk]*wv[kk].z;
          acc[mi][3] += xp[kk]*wv[kk].w;
        }
      }
    }
  }
}

// ---------------- internal level: full fused node update (in-place slot contraction).
// FUSE_LEAF: children are leaf nodes, computed on the fly from targets.
template<bool FUSE_LEAF>
__global__ __launch_bounds__(256,2)
void level_kernel(const float* __restrict__ targets, const float* __restrict__ mask,
                  float* __restrict__ buf, int S,    // node j: slot j*S ; children at j*S, j*S+S/2
                  const float* __restrict__ wir_w, const float* __restrict__ wir_b,
                  const float* __restrict__ whr_w, const float* __restrict__ whr_b,
                  const float* __restrict__ wiz_w, const float* __restrict__ wiz_b,
                  const float* __restrict__ whz_w, const float* __restrict__ whz_b,
                  const float* __restrict__ win_w, const float* __restrict__ win_b,
                  const float* __restrict__ whn_w, const float* __restrict__ whn_b,
                  const float* __restrict__ wms_w, const float* __restrict__ wms_b,
                  const float* __restrict__ w_w,  const float* __restrict__ w_b,
                  const float* __restrict__ wa_w, const float* __restrict__ wa_b,
                  int start)
{
  __shared__ float c0s[TM][PAD];   // c0, later overwritten with g
  __shared__ float c1s[TM][PAD];   // c1, later s, later child_sum
  __shared__ float xsm[TM][I_];
  __shared__ float x0sm[TM][I_];
  __shared__ float x1sm[TM][I_];
  __shared__ float Wb[16][PAD];
  __shared__ float msk[TM], mk0[TM], mk1[TM];

  const int tid = threadIdx.x;
  const int cg = tid & 63, rg = tid >> 6;
  const int n0 = cg*4, m0 = rg*4;
  const long gr0 = (long)blockIdx.x * TM;
  const int node = (int)(gr0 / B_);
  const int b0   = (int)(gr0 % B_);

  const size_t slot = (size_t)node * S * B_ * H_;   // output slot == c0 slot
  float* hout = buf + slot + (size_t)b0 * H_;

  // own x + mask
  const float* xg = targets + ((size_t)(start+node)*B_ + b0)*I_;
  if (tid < 128){
    int m = tid>>3, kq = tid&7;
    *(float4*)&xsm[m][4*kq] = *(const float4*)(xg + m*I_ + 4*kq);
  }
  if (tid < TM) msk[tid] = mask[(size_t)(start+node)*B_ + b0 + tid];

  float acc[4][4];

  if (FUSE_LEAF){
    // children are leaves 63+2*node, 64+2*node: h = (1-z)*n * leafmask
    const float* x0g = targets + ((size_t)(63+2*node)*B_ + b0)*I_;
    const float* x1g = x0g + (size_t)B_*I_;
    if (tid < 128){
      int m = tid>>3, kq = tid&7;
      *(float4*)&x0sm[m][4*kq] = *(const float4*)(x0g + m*I_ + 4*kq);
      *(float4*)&x1sm[m][4*kq] = *(const float4*)(x1g + m*I_ + 4*kq);
    }
    if (tid < TM){
      mk0[tid] = mask[(size_t)(63+2*node)*B_ + b0 + tid];
      mk1[tid] = mask[(size_t)(64+2*node)*B_ + b0 + tid];
    }
    float4 bz1=*(const float4*)(wiz_b+n0), bz2=*(const float4*)(whz_b+n0);
    float4 bn1=*(const float4*)(win_b+n0), bn2=*(const float4*)(whn_b+n0);
    const float *bz1p=(const float*)&bz1, *bz2p=(const float*)&bz2;
    const float *bn1p=(const float*)&bn1, *bn2p=(const float*)&bn2;
    float za[4][4];
    gemm_tile<I_, I_>(wiz_w, &x0sm[0][0], Wb, tid, m0, n0, za);
    gemm_tile<I_, I_>(win_w, &x0sm[0][0], Wb, tid, m0, n0, acc);
#pragma unroll
    for (int mi=0;mi<4;++mi){
      float hm = mk0[m0+mi];
#pragma unroll
      for (int ni=0;ni<4;++ni){
        float z  = sigf(za[mi][ni]+bz1p[ni]+bz2p[ni]);
        float nn = tanhf(acc[mi][ni]+bn1p[ni]+bn2p[ni]);
        c0s[m0+mi][n0+ni] = (1.f-z)*nn*hm;
      }
    }
    gemm_tile<I_, I_>(wiz_w, &x1sm[0][0], Wb, tid, m0, n0, za);
    gemm_tile<I_, I_>(win_w, &x1sm[0][0], Wb, tid, m0, n0, acc);
#pragma unroll
    for (int mi=0;mi<4;++mi){
      float hm = mk1[m0+mi];
#pragma unroll
      for (int ni=0;ni<4;++ni){
        float z  = sigf(za[mi][ni]+bz1p[ni]+bz2p[ni]);
        float nn = tanhf(acc[mi][ni]+bn1p[ni]+bn2p[ni]);
        c1s[m0+mi][n0+ni] = (1.f-z)*nn*hm;
      }
    }
  } else {
    // stage children hidden (fp32) from slots S*node, S*node + S/2
    const float* c0g = buf + slot + (size_t)b0 * H_;
    const float* c1g = c0g + (size_t)(S>>1) * B_ * H_;
#pragma unroll
    for (int i=0;i<4;++i){
      int q = i*256+tid;             // 1024 float4s = 16 rows x 256 cols
      int m = q>>6, kq = q&63;
      *(float4*)&c0s[m][4*kq] = *(const float4*)(c0g + (size_t)m*H_ + 4*kq);
      *(float4*)&c1s[m][4*kq] = *(const float4*)(c1g + (size_t)m*H_ + 4*kq);
    }
  }

  float xr[4][4], xz[4][4], xn[4][4];

  // x projections (include input bias)
  gemm_tile<I_, I_>(wir_w, &xsm[0][0], Wb, tid, m0, n0, acc);
  { float4 b=*(const float4*)(wir_b+n0); const float* bp=(const float*)&b;
#pragma unroll
    for (int mi=0;mi<4;++mi)
#pragma unroll
      for (int ni=0;ni<4;++ni) xr[mi][ni]=acc[mi][ni]+bp[ni]; }
  gemm_tile<I_, I_>(wiz_w, &xsm[0][0], Wb, tid, m0, n0, acc);
  { float4 b=*(const float4*)(wiz_b+n0); const float* bp=(const float*)&b;
#pragma unroll
    for (int mi=0;mi<4;++mi)
#pragma unroll
      for (int ni=0;ni<4;++ni) xz[mi][ni]=acc[mi][ni]+bp[ni]; }
  gemm_tile<I_, I_>(win_w, &xsm[0][0], Wb, tid, m0, n0, acc);
  { float4 b=*(const float4*)(win_b+n0); const float* bp=(const float*)&b;
#pragma unroll
    for (int mi=0;mi<4;++mi)
#pragma unroll
      for (int ni=0;ni<4;++ni) xn[mi][ni]=acc[mi][ni]+bp[ni]; }

  // ms_k = tanh(c_k @ wms_k^T + wms_b_k); score_k = ms_k . w_w + w_b (rows wave-local)
  float s0[4], s1[4];
  {
    gemm_tile<H_, PAD>(wms_w, &c0s[0][0], Wb, tid, m0, n0, acc);
    float4 b=*(const float4*)(wms_b+n0); float4 ww=*(const float4*)(w_w+n0);
    const float* bp=(const float*)&b; const float* wp=(const float*)&ww;
#pragma unroll
    for (int mi=0;mi<4;++mi){
      float p=0.f;
#pragma unroll
      for (int ni=0;ni<4;++ni) p += tanhf(acc[mi][ni]+bp[ni])*wp[ni];
#pragma unroll
      for (int off=32; off>0; off>>=1) p += __shfl_xor(p, off);
      s0[mi] = p + w_b[0];
    }
  }
  {
    gemm_tile<H_, PAD>(wms_w + H_*H_, &c1s[0][0], Wb, tid, m0, n0, acc);
    float4 b=*(const float4*)(wms_b+H_+n0); float4 ww=*(const float4*)(w_w+n0);
    const float* bp=(const float*)&b; const float* wp=(const float*)&ww;
#pragma unroll
    for (int mi=0;mi<4;++mi){
      float p=0.f;
#pragma unroll
      for (int ni=0;ni<4;++ni) p += tanhf(acc[mi][ni]+bp[ni])*wp[ni];
#pragma unroll
      for (int off=32; off>0; off>>=1) p += __shfl_xor(p, off);
      s1[mi] = p + w_b[0];
    }
  }
  float a0[4], a1[4];
#pragma unroll
  for (int mi=0;mi<4;++mi){ float s=s0[mi]+s1[mi]; a0[mi]=s0[mi]/s; a1[mi]=s1[mi]/s; }

  // r_k = sigmoid(xi_r + c_k@whr^T + whr_b);  s = r0*c0 + r1*c1
  float ss[4][4];
  {
    gemm_tile<H_, PAD>(whr_w, &c0s[0][0], Wb, tid, m0, n0, acc);
    float4 b=*(const float4*)(whr_b+n0); const float* bp=(const float*)&b;
#pragma unroll
    for (int mi=0;mi<4;++mi)
#pragma unroll
      for (int ni=0;ni<4;++ni){
        float r = sigf(acc[mi][ni]+xr[mi][ni]+bp[ni]);
        ss[mi][ni] = r*c0s[m0+mi][n0+ni];
      }
  }
  {
    gemm_tile<H_, PAD>(whr_w, &c1s[0][0], Wb, tid, m0, n0, acc);
    float4 b=*(const float4*)(whr_b+n0); const float* bp=(const float*)&b;
#pragma unroll
    for (int mi=0;mi<4;++mi)
#pragma unroll
      for (int ni=0;ni<4;++ni){
        float r = sigf(acc[mi][ni]+xr[mi][ni]+bp[ni]);
        ss[mi][ni] += r*c1s[m0+mi][n0+ni];
      }
  }

  // g = a0*c0 + a1*c1 ; overwrite c0s<-g, c1s<-s (own tiles; rows wave-exclusive)
#pragma unroll
  for (int mi=0;mi<4;++mi)
#pragma unroll
    for (int ni=0;ni<4;++ni){
      float gvv = a0[mi]*c0s[m0+mi][n0+ni] + a1[mi]*c1s[m0+mi][n0+ni];
      c0s[m0+mi][n0+ni] = gvv;
      c1s[m0+mi][n0+ni] = ss[mi][ni];
    }

  // child_sum = tanh(g @ wa^T + wa_b)
  float cs[4][4];
  {
    gemm_tile<H_, PAD>(wa_w, &c0s[0][0], Wb, tid, m0, n0, acc);
    float4 b=*(const float4*)(wa_b+n0); const float* bp=(const float*)&b;
#pragma unroll
    for (int mi=0;mi<4;++mi)
#pragma unroll
      for (int ni=0;ni<4;++ni) cs[mi][ni]=tanhf(acc[mi][ni]+bp[ni]);
  }

  // n = tanh(xn + s @ whn^T + whn_b)
  float nn[4][4];
  {
    gemm_tile<H_, PAD>(whn_w, &c1s[0][0], Wb, tid, m0, n0, acc);
    float4 b=*(const float4*)(whn_b+n0); const float* bp=(const float*)&b;
#pragma unroll
    for (int mi=0;mi<4;++mi)
#pragma unroll
      for (int ni=0;ni<4;++ni) nn[mi][ni]=tanhf(acc[mi][ni]+xn[mi][ni]+bp[ni]);
  }

  // c1s now dead -> store child_sum there for the whz GEMM
#pragma unroll
  for (int mi=0;mi<4;++mi)
#pragma unroll
    for (int ni=0;ni<4;++ni) c1s[m0+mi][n0+ni]=cs[mi][ni];

  // z = sigmoid(xz + cs @ whz^T + whz_b); h = (1-z)*n + z*cs; write h*mask (in place over c0 slot)
  {
    gemm_tile<H_, PAD>(whz_w, &c1s[0][0], Wb, tid, m0, n0, acc);
    float4 b=*(const float4*)(whz_b+n0); const float* bp=(const float*)&b;
#pragma unroll
    for (int mi=0;mi<4;++mi){
      float hm = msk[m0+mi];
      float4 o; float* op=(float*)&o;
#pragma unroll
      for (int ni=0;ni<4;++ni){
        float z = sigf(acc[mi][ni]+xz[mi][ni]+bp[ni]);
        float h = (1.f-z)*nn[mi][ni] + z*cs[mi][ni];
        op[ni] = h*hm;
      }
      *(float4*)(hout + (size_t)(m0+mi)*H_ + n0) = o;
    }
  }
}

// ---------------- output heads: mu = root@mu_w^T+mu_b ; lv = root@lv_w^T+lv_b
__global__ __launch_bounds__(256)
void head_kernel(const float* __restrict__ root,
                 const float* __restrict__ mu_w, const float* __restrict__ mu_b,
                 const float* __restrict__ lv_w, const float* __restrict__ lv_b,
                 float* __restrict__ out)
{
  __shared__ float rs[32][PAD];
  const int tid = threadIdx.x;
  const int r0 = blockIdx.x*32;
#pragma unroll
  for (int i=0;i<8;++i){
    int q = i*256+tid;              // 2048 float4s = 32 rows x 256 cols
    int m=q>>6, kq=q&63;
    *(float4*)&rs[m][4*kq] = *(const float4*)(root + (size_t)(r0+m)*H_ + 4*kq);
  }
  __syncthreads();
  const float* W; float bias; float* ob;
  if (tid<128){ W = mu_w + tid*H_; bias = mu_b[tid]; ob = out + tid; }
  else        { W = lv_w + (tid-128)*H_; bias = lv_b[tid-128]; ob = out + (size_t)B_*128 + (tid-128); }
  float acc[32];
#pragma unroll
  for (int m=0;m<32;++m) acc[m]=0.f;
  for (int k0=0;k0<H_;k0+=8){
    float4 w0=*(const float4*)(W+k0), w1=*(const float4*)(W+k0+4);
#pragma unroll
    for (int m=0;m<32;++m){
      float4 x0=*(const float4*)&rs[m][k0], x1=*(const float4*)&rs[m][k0+4];
      acc[m] += x0.x*w0.x + x0.y*w0.y + x0.z*w0.z + x0.w*w0.w
              + x1.x*w1.x + x1.y*w1.y + x1.z*w1.z + x1.w*w1.w;
    }
  }
#pragma unroll
  for (int m=0;m<32;++m) ob[(size_t)(r0+m)*128] = acc[m] + bias;
}

extern "C" void kernel_launch(void* const* d_in, const int* in_sizes, int n_in,
                              void* d_out, int out_size, void* d_ws, size_t ws_size,
                              hipStream_t stream)
{
  (void)in_sizes; (void)n_in; (void)out_size; (void)d_ws; (void)ws_size;
  const float* targets = (const float*)d_in[0];
  const float* mask    = (const float*)d_in[1];
  const float* wir_w = (const float*)d_in[2];
  const float* wir_b = (const float*)d_in[3];
  const float* whr_w = (const float*)d_in[4];
  const float* whr_b = (const float*)d_in[5];
  const float* wiz_w = (const float*)d_in[6];
  const float* wiz_b = (const float*)d_in[7];
  const float* whz_w = (const float*)d_in[8];
  const float* whz_b = (const float*)d_in[9];
  const float* win_w = (const float*)d_in[10];
  const float* win_b = (const float*)d_in[11];
  const float* whn_w = (const float*)d_in[12];
  const float* whn_b = (const float*)d_in[13];
  const float* wms_w = (const float*)d_in[14];
  const float* wms_b = (const float*)d_in[15];
  const float* w_w   = (const float*)d_in[16];
  const float* w_b   = (const float*)d_in[17];
  const float* wa_w  = (const float*)d_in[18];
  const float* wa_b  = (const float*)d_in[19];
  const float* mu_w  = (const float*)d_in[20];
  const float* mu_b  = (const float*)d_in[21];
  const float* lv_w  = (const float*)d_in[22];
  const float* lv_b  = (const float*)d_in[23];
  float* out = (float*)d_out;

  float* buf;
  hipGetSymbolAddress((void**)&buf, HIP_SYMBOL(g_hid));   // host-side query, graph-capture safe

  // level d=5 with fused leaf children (start=31, 32 nodes -> slots 0..31, S=1)
  level_kernel<true><<<32*B_/TM, 256, 0, stream>>>(targets, mask, buf, 1,
      wir_w, wir_b, whr_w, whr_b, wiz_w, wiz_b, whz_w, whz_b,
      win_w, win_b, whn_w, whn_b, wms_w, wms_b, w_w, w_b, wa_w, wa_b, 31);

  // levels d=4..0: S = 2^(5-d); in-place contraction, root lands at slot 0
  for (int d=4; d>=0; --d){
    int S = 1 << (5-d);
    level_kernel<false><<<((1<<d)*B_)/TM, 256, 0, stream>>>(targets, mask, buf, S,
        wir_w, wir_b, whr_w, whr_b, wiz_w, wiz_b, whz_w, whz_b,
        win_w, win_b, whn_w, whn_b, wms_w, wms_b, w_w, w_b, wa_w, wa_b,
        (1<<d)-1);
  }

  head_kernel<<<B_/32, 256, 0, stream>>>(buf, mu_w, mu_b, lv_w, lv_b, out);
}

// Round 5
// 18215.457 us; speedup vs baseline: 1.1275x; 1.1275x over previous
//
#include <hip/hip_runtime.h>
#include <hip/hip_bf16.h>

#define B_ 4096
#define H_ 256
#define I_ 32
#define TM 64     // rows per block
#define NTHR 512  // 8 waves; wave w owns rows 8w..8w+7, lane owns 4 cols
#define PAD 260

typedef float f4_ __attribute__((ext_vector_type(4)));

// Static inter-level hidden buffer: 32 slots of (B x H) fp32 = 128 MiB.
// In-place binary-tree contraction: level-d node j occupies slot j*2^(5-d).
__device__ float g_hid[(size_t)32 * B_ * H_];

__device__ __forceinline__ float sigf(float x){ return 1.0f/(1.0f+__expf(-x)); }

struct SM {
  float Xs[TM][PAD];      // rotating X operand: c0 -> c1 -> g -> s -> child_sum (rows wave-local)
  float Wb[2][16][PAD];   // double-buffered weight k-chunks, [k][n] transposed
  float xsm[TM][I_];      // parent x (resident)
  float xbuf[TM][I_];     // leaf-child x (FUSE_LEAF scratch)
};

// out[64x256] = X(64 x K) @ W(256 x K)^T. Per-thread: 8 rows x 4 cols.
// Weight chunks (16 k) prefetched to regs AFTER the barrier so the global
// latency overlaps the chunk compute; ds_write consumes them at iter end.
template<int K, int XS>
__device__ __forceinline__ void gemm64(const float* __restrict__ W,
                                       const float* __restrict__ X,   // LDS, row stride XS
                                       float (*Wb)[16][PAD],          // [2][16][PAD]
                                       int tid, int m0, int n0,
                                       f4_ acc[8])
{
  constexpr int NC = K/16;
#pragma unroll
  for (int mi=0;mi<8;++mi) acc[mi] = (f4_)0.f;

  f4_ pre0, pre1;
  {
    const int i0 = tid, i1 = NTHR + tid;
    pre0 = *(const f4_*)(W + (size_t)(i0>>2)*K + 4*(i0&3));
    pre1 = *(const f4_*)(W + (size_t)(i1>>2)*K + 4*(i1&3));
  }
  __syncthreads();                    // prior Wb readers done
  {
    const int i0 = tid, i1 = NTHR + tid;
    int n0w = i0>>2, j0 = i0&3, n1w = i1>>2, j1 = i1&3;
    Wb[0][4*j0+0][n0w]=pre0.x; Wb[0][4*j0+1][n0w]=pre0.y;
    Wb[0][4*j0+2][n0w]=pre0.z; Wb[0][4*j0+3][n0w]=pre0.w;
    Wb[0][4*j1+0][n1w]=pre1.x; Wb[0][4*j1+1][n1w]=pre1.y;
    Wb[0][4*j1+2][n1w]=pre1.z; Wb[0][4*j1+3][n1w]=pre1.w;
  }

  for (int c=0; c<NC; ++c){
    __syncthreads();                  // Wb[c&1] visible; all waves past previous compute
    const int kb = c*16;
    if (c+1 < NC){                    // issue next chunk loads (overlap with compute below)
      const int i0 = tid, i1 = NTHR + tid;
      pre0 = *(const f4_*)(W + (size_t)(i0>>2)*K + kb+16 + 4*(i0&3));
      pre1 = *(const f4_*)(W + (size_t)(i1>>2)*K + kb+16 + 4*(i1&3));
    }
    const int b = c & 1;
#pragma unroll
    for (int ku=0; ku<4; ++ku){
      f4_ wv0 = *(const f4_*)&Wb[b][4*ku+0][n0];
      f4_ wv1 = *(const f4_*)&Wb[b][4*ku+1][n0];
      f4_ wv2 = *(const f4_*)&Wb[b][4*ku+2][n0];
      f4_ wv3 = *(const f4_*)&Wb[b][4*ku+3][n0];
#pragma unroll
      for (int mi=0; mi<8; ++mi){
        f4_ xv = *(const f4_*)(X + (m0+mi)*XS + kb + 4*ku);  // wave-broadcast read
        acc[mi] += xv.x*wv0 + xv.y*wv1 + xv.z*wv2 + xv.w*wv3;
      }
    }
    if (c+1 < NC){
      const int b2 = (c+1)&1;
      const int i0 = tid, i1 = NTHR + tid;
      int n0w = i0>>2, j0 = i0&3, n1w = i1>>2, j1 = i1&3;
      Wb[b2][4*j0+0][n0w]=pre0.x; Wb[b2][4*j0+1][n0w]=pre0.y;
      Wb[b2][4*j0+2][n0w]=pre0.z; Wb[b2][4*j0+3][n0w]=pre0.w;
      Wb[b2][4*j1+0][n1w]=pre1.x; Wb[b2][4*j1+1][n1w]=pre1.y;
      Wb[b2][4*j1+2][n1w]=pre1.z; Wb[b2][4*j1+3][n1w]=pre1.w;
    }
  }
}

// ---------------- fused level kernel (in-place slot contraction) ----------------
template<bool FUSE_LEAF>
__global__ __launch_bounds__(NTHR, 2)
void level_kernel(const float* __restrict__ targets, const float* __restrict__ mask,
                  float* __restrict__ buf, int S,    // node j: slot j*S ; children at j*S, j*S+S/2
                  const float* __restrict__ wir_w, const float* __restrict__ wir_b,
                  const float* __restrict__ whr_w, const float* __restrict__ whr_b,
                  const float* __restrict__ wiz_w, const float* __restrict__ wiz_b,
                  const float* __restrict__ whz_w, const float* __restrict__ whz_b,
                  const float* __restrict__ win_w, const float* __restrict__ win_b,
                  const float* __restrict__ whn_w, const float* __restrict__ whn_b,
                  const float* __restrict__ wms_w, const float* __restrict__ wms_b,
                  const float* __restrict__ w_w,  const float* __restrict__ w_b,
                  const float* __restrict__ wa_w, const float* __restrict__ wa_b,
                  int start)
{
  __shared__ SM sm;
  const int tid  = threadIdx.x;
  const int w    = tid >> 6, lane = tid & 63;
  const int m0   = w*8, n0 = lane*4;
  const long gr0 = (long)blockIdx.x * TM;
  const int node = (int)(gr0 / B_);
  const int b0   = (int)(gr0 % B_);
  const size_t slot = (size_t)node * S * B_ * H_;
  float* hout = buf + slot + (size_t)b0 * H_;

  // stage parent x (wave-local rows: lane -> row m0+(lane>>3), quad lane&7)
  {
    const float* xg = targets + ((size_t)(start+node)*B_ + b0)*I_;
    int r = m0 + (lane>>3), q = lane & 7;
    *(f4_*)&sm.xsm[r][4*q] = __builtin_nontemporal_load((const f4_*)(xg + (size_t)r*I_ + 4*q));
  }

  f4_ acc[8], rc0[8], rc1[8], ss[8], xr[8];
  float s0[8], s1[8];

  // ---- child 0 into Xs + rc0 ----
  if (FUSE_LEAF){
    {
      const float* x0g = targets + ((size_t)(63+2*node)*B_ + b0)*I_;
      int r = m0 + (lane>>3), q = lane & 7;
      *(f4_*)&sm.xbuf[r][4*q] = __builtin_nontemporal_load((const f4_*)(x0g + (size_t)r*I_ + 4*q));
    }
    f4_ za[8];
    gemm64<I_, I_>(wiz_w, &sm.xbuf[0][0], sm.Wb, tid, m0, n0, za);
    gemm64<I_, I_>(win_w, &sm.xbuf[0][0], sm.Wb, tid, m0, n0, acc);
    {
      f4_ bz1=*(const f4_*)(wiz_b+n0), bz2=*(const f4_*)(whz_b+n0);
      f4_ bn1=*(const f4_*)(win_b+n0), bn2=*(const f4_*)(whn_b+n0);
      const float* mk = mask + (size_t)(63+2*node)*B_ + b0;
#pragma unroll
      for (int mi=0;mi<8;++mi){
        float hm = mk[m0+mi];
        f4_ v;
#pragma unroll
        for (int j=0;j<4;++j){
          float z  = sigf(za[mi][j]+bz1[j]+bz2[j]);
          float nn = tanhf(acc[mi][j]+bn1[j]+bn2[j]);
          v[j] = (1.f-z)*nn*hm;
        }
        rc0[mi]=v; *(f4_*)&sm.Xs[m0+mi][n0]=v;
      }
    }
  } else {
    const float* c0g = buf + slot + (size_t)b0 * H_;
#pragma unroll
    for (int mi=0;mi<8;++mi){
      f4_ v = __builtin_nontemporal_load((const f4_*)(c0g + (size_t)(m0+mi)*H_ + n0));
      rc0[mi]=v; *(f4_*)&sm.Xs[m0+mi][n0]=v;
    }
  }

  // ---- ms0 -> s0 ----
  gemm64<H_, PAD>(wms_w, &sm.Xs[0][0], sm.Wb, tid, m0, n0, acc);
  {
    f4_ b=*(const f4_*)(wms_b+n0), ww=*(const f4_*)(w_w+n0);
    float wb0 = w_b[0];
#pragma unroll
    for (int mi=0;mi<8;++mi){
      float p = tanhf(acc[mi][0]+b[0])*ww[0] + tanhf(acc[mi][1]+b[1])*ww[1]
              + tanhf(acc[mi][2]+b[2])*ww[2] + tanhf(acc[mi][3]+b[3])*ww[3];
#pragma unroll
      for (int off=32; off>0; off>>=1) p += __shfl_xor(p, off);
      s0[mi] = p + wb0;
    }
  }

  // ---- xr = x@wir^T + b ----
  gemm64<I_, I_>(wir_w, &sm.xsm[0][0], sm.Wb, tid, m0, n0, xr);
  { f4_ b=*(const f4_*)(wir_b+n0);
#pragma unroll
    for (int mi=0;mi<8;++mi) xr[mi] += b; }

  // ---- r0 ; ss = r0*c0 ----
  gemm64<H_, PAD>(whr_w, &sm.Xs[0][0], sm.Wb, tid, m0, n0, acc);
  { f4_ b=*(const f4_*)(whr_b+n0);
#pragma unroll
    for (int mi=0;mi<8;++mi){
      f4_ r;
#pragma unroll
      for (int j=0;j<4;++j) r[j] = sigf(acc[mi][j]+xr[mi][j]+b[j]);
      ss[mi] = r*rc0[mi];
    }
  }

  // ---- child 1 into Xs + rc1 (Xs rewrite is wave-local; no barrier needed) ----
  if (FUSE_LEAF){
    {
      const float* x1g = targets + ((size_t)(64+2*node)*B_ + b0)*I_;
      int r = m0 + (lane>>3), q = lane & 7;
      *(f4_*)&sm.xbuf[r][4*q] = __builtin_nontemporal_load((const f4_*)(x1g + (size_t)r*I_ + 4*q));
    }
    f4_ za[8];
    gemm64<I_, I_>(wiz_w, &sm.xbuf[0][0], sm.Wb, tid, m0, n0, za);
    gemm64<I_, I_>(win_w, &sm.xbuf[0][0], sm.Wb, tid, m0, n0, acc);
    {
      f4_ bz1=*(const f4_*)(wiz_b+n0), bz2=*(const f4_*)(whz_b+n0);
      f4_ bn1=*(const f4_*)(win_b+n0), bn2=*(const f4_*)(whn_b+n0);
      const float* mk = mask + (size_t)(64+2*node)*B_ + b0;
#pragma unroll
      for (int mi=0;mi<8;++mi){
        float hm = mk[m0+mi];
        f4_ v;
#pragma unroll
        for (int j=0;j<4;++j){
          float z  = sigf(za[mi][j]+bz1[j]+bz2[j]);
          float nn = tanhf(acc[mi][j]+bn1[j]+bn2[j]);
          v[j] = (1.f-z)*nn*hm;
        }
        rc1[mi]=v; *(f4_*)&sm.Xs[m0+mi][n0]=v;
      }
    }
  } else {
    const float* c1g = buf + slot + (size_t)(S>>1)*B_*H_ + (size_t)b0*H_;
#pragma unroll
    for (int mi=0;mi<8;++mi){
      f4_ v = __builtin_nontemporal_load((const f4_*)(c1g + (size_t)(m0+mi)*H_ + n0));
      rc1[mi]=v; *(f4_*)&sm.Xs[m0+mi][n0]=v;
    }
  }

  // ---- ms1 -> s1 ----
  gemm64<H_, PAD>(wms_w + H_*H_, &sm.Xs[0][0], sm.Wb, tid, m0, n0, acc);
  {
    f4_ b=*(const f4_*)(wms_b+H_+n0), ww=*(const f4_*)(w_w+n0);
    float wb0 = w_b[0];
#pragma unroll
    for (int mi=0;mi<8;++mi){
      float p = tanhf(acc[mi][0]+b[0])*ww[0] + tanhf(acc[mi][1]+b[1])*ww[1]
              + tanhf(acc[mi][2]+b[2])*ww[2] + tanhf(acc[mi][3]+b[3])*ww[3];
#pragma unroll
      for (int off=32; off>0; off>>=1) p += __shfl_xor(p, off);
      s1[mi] = p + wb0;
    }
  }

  // ---- r1 ; ss += r1*c1 ; g = a0*c0 + a1*c1 -> Xs ----
  gemm64<H_, PAD>(whr_w, &sm.Xs[0][0], sm.Wb, tid, m0, n0, acc);
  { f4_ b=*(const f4_*)(whr_b+n0);
#pragma unroll
    for (int mi=0;mi<8;++mi){
      f4_ r;
#pragma unroll
      for (int j=0;j<4;++j) r[j] = sigf(acc[mi][j]+xr[mi][j]+b[j]);
      ss[mi] += r*rc1[mi];
      float sum = s0[mi]+s1[mi];
      float a0 = s0[mi]/sum, a1 = s1[mi]/sum;
      f4_ gv = a0*rc0[mi] + a1*rc1[mi];
      *(f4_*)&sm.Xs[m0+mi][n0] = gv;
    }
  }

  // ---- child_sum = tanh(g@wa^T + b) ----
  f4_ cs[8];
  gemm64<H_, PAD>(wa_w, &sm.Xs[0][0], sm.Wb, tid, m0, n0, acc);
  { f4_ b=*(const f4_*)(wa_b+n0);
#pragma unroll
    for (int mi=0;mi<8;++mi){
#pragma unroll
      for (int j=0;j<4;++j) cs[mi][j] = tanhf(acc[mi][j]+b[j]);
      *(f4_*)&sm.Xs[m0+mi][n0] = ss[mi];   // stage s for whn (wave-local)
    }
  }

  // ---- xn ; n = tanh(xn + s@whn^T + b) ----
  f4_ xn[8];
  gemm64<I_, I_>(win_w, &sm.xsm[0][0], sm.Wb, tid, m0, n0, xn);
  { f4_ b=*(const f4_*)(win_b+n0);
#pragma unroll
    for (int mi=0;mi<8;++mi) xn[mi] += b; }
  f4_ nn[8];
  gemm64<H_, PAD>(whn_w, &sm.Xs[0][0], sm.Wb, tid, m0, n0, acc);
  { f4_ b=*(const f4_*)(whn_b+n0);
#pragma unroll
    for (int mi=0;mi<8;++mi){
#pragma unroll
      for (int j=0;j<4;++j) nn[mi][j] = tanhf(acc[mi][j]+xn[mi][j]+b[j]);
      *(f4_*)&sm.Xs[m0+mi][n0] = cs[mi];   // stage child_sum for whz (wave-local)
    }
  }

  // ---- xz ; z ; h = (1-z)*n + z*cs ; store h*mask ----
  f4_ xz[8];
  gemm64<I_, I_>(wiz_w, &sm.xsm[0][0], sm.Wb, tid, m0, n0, xz);
  { f4_ b=*(const f4_*)(wiz_b+n0);
#pragma unroll
    for (int mi=0;mi<8;++mi) xz[mi] += b; }
  gemm64<H_, PAD>(whz_w, &sm.Xs[0][0], sm.Wb, tid, m0, n0, acc);
  {
    f4_ b=*(const f4_*)(whz_b+n0);
    const float* mk = mask + (size_t)(start+node)*B_ + b0;
#pragma unroll
    for (int mi=0;mi<8;++mi){
      float hm = mk[m0+mi];
      f4_ o;
#pragma unroll
      for (int j=0;j<4;++j){
        float z = sigf(acc[mi][j]+xz[mi][j]+b[j]);
        o[j] = ((1.f-z)*nn[mi][j] + z*cs[mi][j])*hm;
      }
      __builtin_nontemporal_store(o, (f4_*)(hout + (size_t)(m0+mi)*H_ + n0));
    }
  }
}

// ---------------- output heads: mu = root@mu_w^T+mu_b ; lv = root@lv_w^T+lv_b
__global__ __launch_bounds__(256)
void head_kernel(const float* __restrict__ root,
                 const float* __restrict__ mu_w, const float* __restrict__ mu_b,
                 const float* __restrict__ lv_w, const float* __restrict__ lv_b,
                 float* __restrict__ out)
{
  __shared__ float rs[32][PAD];
  const int tid = threadIdx.x;
  const int r0 = blockIdx.x*32;
#pragma unroll
  for (int i=0;i<8;++i){
    int q = i*256+tid;
    int m=q>>6, kq=q&63;
    *(float4*)&rs[m][4*kq] = *(const float4*)(root + (size_t)(r0+m)*H_ + 4*kq);
  }
  __syncthreads();
  const float* W; float bias; float* ob;
  if (tid<128){ W = mu_w + tid*H_; bias = mu_b[tid]; ob = out + tid; }
  else        { W = lv_w + (tid-128)*H_; bias = lv_b[tid-128]; ob = out + (size_t)B_*128 + (tid-128); }
  float acc[32];
#pragma unroll
  for (int m=0;m<32;++m) acc[m]=0.f;
  for (int k0=0;k0<H_;k0+=8){
    float4 w0=*(const float4*)(W+k0), w1=*(const float4*)(W+k0+4);
#pragma unroll
    for (int m=0;m<32;++m){
      float4 x0=*(const float4*)&rs[m][k0], x1=*(const float4*)&rs[m][k0+4];
      acc[m] += x0.x*w0.x + x0.y*w0.y + x0.z*w0.z + x0.w*w0.w
              + x1.x*w1.x + x1.y*w1.y + x1.z*w1.z + x1.w*w1.w;
    }
  }
#pragma unroll
  for (int m=0;m<32;++m) ob[(size_t)(r0+m)*128] = acc[m] + bias;
}

extern "C" void kernel_launch(void* const* d_in, const int* in_sizes, int n_in,
                              void* d_out, int out_size, void* d_ws, size_t ws_size,
                              hipStream_t stream)
{
  (void)in_sizes; (void)n_in; (void)out_size; (void)d_ws; (void)ws_size;
  const float* targets = (const float*)d_in[0];
  const float* mask    = (const float*)d_in[1];
  const float* wir_w = (const float*)d_in[2];
  const float* wir_b = (const float*)d_in[3];
  const float* whr_w = (const float*)d_in[4];
  const float* whr_b = (const float*)d_in[5];
  const float* wiz_w = (const float*)d_in[6];
  const float* wiz_b = (const float*)d_in[7];
  const float* whz_w = (const float*)d_in[8];
  const float* whz_b = (const float*)d_in[9];
  const float* win_w = (const float*)d_in[10];
  const float* win_b = (const float*)d_in[11];
  const float* whn_w = (const float*)d_in[12];
  const float* whn_b = (const float*)d_in[13];
  const float* wms_w = (const float*)d_in[14];
  const float* wms_b = (const float*)d_in[15];
  const float* w_w   = (const float*)d_in[16];
  const float* w_b   = (const float*)d_in[17];
  const float* wa_w  = (const float*)d_in[18];
  const float* wa_b  = (const float*)d_in[19];
  const float* mu_w  = (const float*)d_in[20];
  const float* mu_b  = (const float*)d_in[21];
  const float* lv_w  = (const float*)d_in[22];
  const float* lv_b  = (const float*)d_in[23];
  float* out = (float*)d_out;

  float* buf;
  hipGetSymbolAddress((void**)&buf, HIP_SYMBOL(g_hid));   // host-side query, graph-capture safe

  // level d=5 with fused leaf children (start=31, 32 nodes -> slots 0..31, S=1)
  level_kernel<true><<<32*B_/TM, NTHR, 0, stream>>>(targets, mask, buf, 1,
      wir_w, wir_b, whr_w, whr_b, wiz_w, wiz_b, whz_w, whz_b,
      win_w, win_b, whn_w, whn_b, wms_w, wms_b, w_w, w_b, wa_w, wa_b, 31);

  // levels d=4..0: S = 2^(5-d); in-place contraction, root lands at slot 0
  for (int d=4; d>=0; --d){
    int S = 1 << (5-d);
    level_kernel<false><<<((1<<d)*B_)/TM, NTHR, 0, stream>>>(targets, mask, buf, S,
        wir_w, wir_b, whr_w, whr_b, wiz_w, wiz_b, whz_w, whz_b,
        win_w, win_b, whn_w, whn_b, wms_w, wms_b, w_w, w_b, wa_w, wa_b,
        (1<<d)-1);
  }

  head_kernel<<<B_/32, 256, 0, stream>>>(buf, mu_w, mu_b, lv_w, lv_b, out);
}

// Round 6
// 16369.070 us; speedup vs baseline: 1.2547x; 1.1128x over previous
//
#include <hip/hip_runtime.h>
#include <hip/hip_bf16.h>

#define B_ 4096
#define H_ 256
#define I_ 32
#define TM 64     // rows per block
#define NTHR 512  // 8 waves; wave w owns rows 8w..8w+7, lane owns 4 cols
#define PAD 260

typedef float f4_ __attribute__((ext_vector_type(4)));

// Static inter-level hidden buffer: 32 slots of (B x H) fp32 = 128 MiB.
// In-place binary-tree contraction: level-d node j occupies slot j*2^(5-d).
__device__ float g_hid[(size_t)32 * B_ * H_];

__device__ __forceinline__ float sigf(float x){ return 1.0f/(1.0f+__expf(-x)); }

struct SM {
  float Xs[TM][PAD];      // rotating X operand: c0 -> c1 -> g -> s -> child_sum (rows wave-private)
  float Wb[2][16][PAD];   // double-buffered weight k-chunks, [k][n] transposed
  float xsm[TM][I_];      // parent x (resident)
  float xbuf[TM][I_];     // leaf-child x (FUSE_LEAF scratch)
};

// out[64x256] = X(64 x K) @ W(256 x K)^T. Per-thread: 8 rows x 4 cols.
// Weight chunks (16 k) prefetched to regs AFTER the barrier so the global
// latency overlaps the chunk compute; ds_write consumes them at iter end.
template<int K, int XS>
__device__ __forceinline__ void gemm64(const float* __restrict__ W,
                                       const float* __restrict__ X,   // LDS, row stride XS
                                       float (*Wb)[16][PAD],          // [2][16][PAD]
                                       int tid, int m0, int n0,
                                       f4_ acc[8])
{
  constexpr int NC = K/16;
#pragma unroll
  for (int mi=0;mi<8;++mi) acc[mi] = (f4_)0.f;

  f4_ pre0, pre1;
  {
    const int i0 = tid, i1 = NTHR + tid;
    pre0 = *(const f4_*)(W + (size_t)(i0>>2)*K + 4*(i0&3));
    pre1 = *(const f4_*)(W + (size_t)(i1>>2)*K + 4*(i1&3));
  }
  __syncthreads();                    // prior Wb readers done
  {
    const int i0 = tid, i1 = NTHR + tid;
    int n0w = i0>>2, j0 = i0&3, n1w = i1>>2, j1 = i1&3;
    Wb[0][4*j0+0][n0w]=pre0.x; Wb[0][4*j0+1][n0w]=pre0.y;
    Wb[0][4*j0+2][n0w]=pre0.z; Wb[0][4*j0+3][n0w]=pre0.w;
    Wb[0][4*j1+0][n1w]=pre1.x; Wb[0][4*j1+1][n1w]=pre1.y;
    Wb[0][4*j1+2][n1w]=pre1.z; Wb[0][4*j1+3][n1w]=pre1.w;
  }

  for (int c=0; c<NC; ++c){
    __syncthreads();                  // Wb[c&1] visible; all waves past previous compute
    const int kb = c*16;
    if (c+1 < NC){                    // issue next chunk loads (overlap with compute below)
      const int i0 = tid, i1 = NTHR + tid;
      pre0 = *(const f4_*)(W + (size_t)(i0>>2)*K + kb+16 + 4*(i0&3));
      pre1 = *(const f4_*)(W + (size_t)(i1>>2)*K + kb+16 + 4*(i1&3));
    }
    const int b = c & 1;
#pragma unroll
    for (int ku=0; ku<4; ++ku){
      f4_ wv0 = *(const f4_*)&Wb[b][4*ku+0][n0];
      f4_ wv1 = *(const f4_*)&Wb[b][4*ku+1][n0];
      f4_ wv2 = *(const f4_*)&Wb[b][4*ku+2][n0];
      f4_ wv3 = *(const f4_*)&Wb[b][4*ku+3][n0];
#pragma unroll
      for (int mi=0; mi<8; ++mi){
        f4_ xv = *(const f4_*)(X + (m0+mi)*XS + kb + 4*ku);  // wave-private row read
        acc[mi] += xv.x*wv0 + xv.y*wv1 + xv.z*wv2 + xv.w*wv3;
      }
    }
    if (c+1 < NC){
      const int b2 = (c+1)&1;
      const int i0 = tid, i1 = NTHR + tid;
      int n0w = i0>>2, j0 = i0&3, n1w = i1>>2, j1 = i1&3;
      Wb[b2][4*j0+0][n0w]=pre0.x; Wb[b2][4*j0+1][n0w]=pre0.y;
      Wb[b2][4*j0+2][n0w]=pre0.z; Wb[b2][4*j0+3][n0w]=pre0.w;
      Wb[b2][4*j1+0][n1w]=pre1.x; Wb[b2][4*j1+1][n1w]=pre1.y;
      Wb[b2][4*j1+2][n1w]=pre1.z; Wb[b2][4*j1+3][n1w]=pre1.w;
    }
  }
}

// ---------------- fused level kernel (in-place slot contraction) ----------------
// launch_bounds(512, 1): 1 block/CU -> 2 waves/SIMD -> 256-VGPR budget.
// Peak live set ~205 VGPRs (acc+rc0+rc1+ss+xr at the r1 epilogue); (512,2)'s
// 128-VGPR cap caused ~25 GB/dispatch scratch spill traffic (r5 post-mortem).
template<bool FUSE_LEAF>
__global__ __launch_bounds__(NTHR, 1)
void level_kernel(const float* __restrict__ targets, const float* __restrict__ mask,
                  float* __restrict__ buf, int S,    // node j: slot j*S ; children at j*S, j*S+S/2
                  const float* __restrict__ wir_w, const float* __restrict__ wir_b,
                  const float* __restrict__ whr_w, const float* __restrict__ whr_b,
                  const float* __restrict__ wiz_w, const float* __restrict__ wiz_b,
                  const float* __restrict__ whz_w, const float* __restrict__ whz_b,
                  const float* __restrict__ win_w, const float* __restrict__ win_b,
                  const float* __restrict__ whn_w, const float* __restrict__ whn_b,
                  const float* __restrict__ wms_w, const float* __restrict__ wms_b,
                  const float* __restrict__ w_w,  const float* __restrict__ w_b,
                  const float* __restrict__ wa_w, const float* __restrict__ wa_b,
                  int start)
{
  __shared__ SM sm;
  const int tid  = threadIdx.x;
  const int w    = tid >> 6, lane = tid & 63;
  const int m0   = w*8, n0 = lane*4;
  const long gr0 = (long)blockIdx.x * TM;
  const int node = (int)(gr0 / B_);
  const int b0   = (int)(gr0 % B_);
  const size_t slot = (size_t)node * S * B_ * H_;
  float* hout = buf + slot + (size_t)b0 * H_;

  // stage parent x (wave-local rows: lane -> row m0+(lane>>3), quad lane&7)
  {
    const float* xg = targets + ((size_t)(start+node)*B_ + b0)*I_;
    int r = m0 + (lane>>3), q = lane & 7;
    *(f4_*)&sm.xsm[r][4*q] = __builtin_nontemporal_load((const f4_*)(xg + (size_t)r*I_ + 4*q));
  }

  f4_ acc[8], rc0[8], rc1[8], ss[8], xr[8];
  float s0[8], s1[8];

  // ---- child 0 into Xs + rc0 ----
  if (FUSE_LEAF){
    {
      const float* x0g = targets + ((size_t)(63+2*node)*B_ + b0)*I_;
      int r = m0 + (lane>>3), q = lane & 7;
      *(f4_*)&sm.xbuf[r][4*q] = __builtin_nontemporal_load((const f4_*)(x0g + (size_t)r*I_ + 4*q));
    }
    f4_ za[8];
    gemm64<I_, I_>(wiz_w, &sm.xbuf[0][0], sm.Wb, tid, m0, n0, za);
    gemm64<I_, I_>(win_w, &sm.xbuf[0][0], sm.Wb, tid, m0, n0, acc);
    {
      f4_ bz1=*(const f4_*)(wiz_b+n0), bz2=*(const f4_*)(whz_b+n0);
      f4_ bn1=*(const f4_*)(win_b+n0), bn2=*(const f4_*)(whn_b+n0);
      const float* mk = mask + (size_t)(63+2*node)*B_ + b0;
#pragma unroll
      for (int mi=0;mi<8;++mi){
        float hm = mk[m0+mi];
        f4_ v;
#pragma unroll
        for (int j=0;j<4;++j){
          float z  = sigf(za[mi][j]+bz1[j]+bz2[j]);
          float nn = tanhf(acc[mi][j]+bn1[j]+bn2[j]);
          v[j] = (1.f-z)*nn*hm;
        }
        rc0[mi]=v; *(f4_*)&sm.Xs[m0+mi][n0]=v;
      }
    }
  } else {
    const float* c0g = buf + slot + (size_t)b0 * H_;
#pragma unroll
    for (int mi=0;mi<8;++mi){
      f4_ v = __builtin_nontemporal_load((const f4_*)(c0g + (size_t)(m0+mi)*H_ + n0));
      rc0[mi]=v; *(f4_*)&sm.Xs[m0+mi][n0]=v;
    }
  }

  // ---- ms0 -> s0 ----
  gemm64<H_, PAD>(wms_w, &sm.Xs[0][0], sm.Wb, tid, m0, n0, acc);
  {
    f4_ b=*(const f4_*)(wms_b+n0), ww=*(const f4_*)(w_w+n0);
    float wb0 = w_b[0];
#pragma unroll
    for (int mi=0;mi<8;++mi){
      float p = tanhf(acc[mi][0]+b[0])*ww[0] + tanhf(acc[mi][1]+b[1])*ww[1]
              + tanhf(acc[mi][2]+b[2])*ww[2] + tanhf(acc[mi][3]+b[3])*ww[3];
#pragma unroll
      for (int off=32; off>0; off>>=1) p += __shfl_xor(p, off);
      s0[mi] = p + wb0;
    }
  }

  // ---- xr = x@wir^T + b ----
  gemm64<I_, I_>(wir_w, &sm.xsm[0][0], sm.Wb, tid, m0, n0, xr);
  { f4_ b=*(const f4_*)(wir_b+n0);
#pragma unroll
    for (int mi=0;mi<8;++mi) xr[mi] += b; }

  // ---- r0 ; ss = r0*c0 ----
  gemm64<H_, PAD>(whr_w, &sm.Xs[0][0], sm.Wb, tid, m0, n0, acc);
  { f4_ b=*(const f4_*)(whr_b+n0);
#pragma unroll
    for (int mi=0;mi<8;++mi){
      f4_ r;
#pragma unroll
      for (int j=0;j<4;++j) r[j] = sigf(acc[mi][j]+xr[mi][j]+b[j]);
      ss[mi] = r*rc0[mi];
    }
  }

  // ---- child 1 into Xs + rc1 (Xs rows wave-private; no barrier needed) ----
  if (FUSE_LEAF){
    {
      const float* x1g = targets + ((size_t)(64+2*node)*B_ + b0)*I_;
      int r = m0 + (lane>>3), q = lane & 7;
      *(f4_*)&sm.xbuf[r][4*q] = __builtin_nontemporal_load((const f4_*)(x1g + (size_t)r*I_ + 4*q));
    }
    f4_ za[8];
    gemm64<I_, I_>(wiz_w, &sm.xbuf[0][0], sm.Wb, tid, m0, n0, za);
    gemm64<I_, I_>(win_w, &sm.xbuf[0][0], sm.Wb, tid, m0, n0, acc);
    {
      f4_ bz1=*(const f4_*)(wiz_b+n0), bz2=*(const f4_*)(whz_b+n0);
      f4_ bn1=*(const f4_*)(win_b+n0), bn2=*(const f4_*)(whn_b+n0);
      const float* mk = mask + (size_t)(64+2*node)*B_ + b0;
#pragma unroll
      for (int mi=0;mi<8;++mi){
        float hm = mk[m0+mi];
        f4_ v;
#pragma unroll
        for (int j=0;j<4;++j){
          float z  = sigf(za[mi][j]+bz1[j]+bz2[j]);
          float nn = tanhf(acc[mi][j]+bn1[j]+bn2[j]);
          v[j] = (1.f-z)*nn*hm;
        }
        rc1[mi]=v; *(f4_*)&sm.Xs[m0+mi][n0]=v;
      }
    }
  } else {
    const float* c1g = buf + slot + (size_t)(S>>1)*B_*H_ + (size_t)b0*H_;
#pragma unroll
    for (int mi=0;mi<8;++mi){
      f4_ v = __builtin_nontemporal_load((const f4_*)(c1g + (size_t)(m0+mi)*H_ + n0));
      rc1[mi]=v; *(f4_*)&sm.Xs[m0+mi][n0]=v;
    }
  }

  // ---- ms1 -> s1 ----
  gemm64<H_, PAD>(wms_w + H_*H_, &sm.Xs[0][0], sm.Wb, tid, m0, n0, acc);
  {
    f4_ b=*(const f4_*)(wms_b+H_+n0), ww=*(const f4_*)(w_w+n0);
    float wb0 = w_b[0];
#pragma unroll
    for (int mi=0;mi<8;++mi){
      float p = tanhf(acc[mi][0]+b[0])*ww[0] + tanhf(acc[mi][1]+b[1])*ww[1]
              + tanhf(acc[mi][2]+b[2])*ww[2] + tanhf(acc[mi][3]+b[3])*ww[3];
#pragma unroll
      for (int off=32; off>0; off>>=1) p += __shfl_xor(p, off);
      s1[mi] = p + wb0;
    }
  }

  // ---- r1 ; ss += r1*c1 ; g = a0*c0 + a1*c1 -> Xs ----
  gemm64<H_, PAD>(whr_w, &sm.Xs[0][0], sm.Wb, tid, m0, n0, acc);
  { f4_ b=*(const f4_*)(whr_b+n0);
#pragma unroll
    for (int mi=0;mi<8;++mi){
      f4_ r;
#pragma unroll
      for (int j=0;j<4;++j) r[j] = sigf(acc[mi][j]+xr[mi][j]+b[j]);
      ss[mi] += r*rc1[mi];
      float sum = s0[mi]+s1[mi];
      float a0 = s0[mi]/sum, a1 = s1[mi]/sum;
      f4_ gv = a0*rc0[mi] + a1*rc1[mi];
      *(f4_*)&sm.Xs[m0+mi][n0] = gv;
    }
  }

  // ---- child_sum = tanh(g@wa^T + b) ----
  f4_ cs[8];
  gemm64<H_, PAD>(wa_w, &sm.Xs[0][0], sm.Wb, tid, m0, n0, acc);
  { f4_ b=*(const f4_*)(wa_b+n0);
#pragma unroll
    for (int mi=0;mi<8;++mi){
#pragma unroll
      for (int j=0;j<4;++j) cs[mi][j] = tanhf(acc[mi][j]+b[j]);
      *(f4_*)&sm.Xs[m0+mi][n0] = ss[mi];   // stage s for whn (wave-private rows)
    }
  }

  // ---- xn ; n = tanh(xn + s@whn^T + b) ----
  f4_ xn[8];
  gemm64<I_, I_>(win_w, &sm.xsm[0][0], sm.Wb, tid, m0, n0, xn);
  { f4_ b=*(const f4_*)(win_b+n0);
#pragma unroll
    for (int mi=0;mi<8;++mi) xn[mi] += b; }
  f4_ nn[8];
  gemm64<H_, PAD>(whn_w, &sm.Xs[0][0], sm.Wb, tid, m0, n0, acc);
  { f4_ b=*(const f4_*)(whn_b+n0);
#pragma unroll
    for (int mi=0;mi<8;++mi){
#pragma unroll
      for (int j=0;j<4;++j) nn[mi][j] = tanhf(acc[mi][j]+xn[mi][j]+b[j]);
      *(f4_*)&sm.Xs[m0+mi][n0] = cs[mi];   // stage child_sum for whz (wave-private rows)
    }
  }

  // ---- xz ; z ; h = (1-z)*n + z*cs ; store h*mask ----
  f4_ xz[8];
  gemm64<I_, I_>(wiz_w, &sm.xsm[0][0], sm.Wb, tid, m0, n0, xz);
  { f4_ b=*(const f4_*)(wiz_b+n0);
#pragma unroll
    for (int mi=0;mi<8;++mi) xz[mi] += b; }
  gemm64<H_, PAD>(whz_w, &sm.Xs[0][0], sm.Wb, tid, m0, n0, acc);
  {
    f4_ b=*(const f4_*)(whz_b+n0);
    const float* mk = mask + (size_t)(start+node)*B_ + b0;
#pragma unroll
    for (int mi=0;mi<8;++mi){
      float hm = mk[m0+mi];
      f4_ o;
#pragma unroll
      for (int j=0;j<4;++j){
        float z = sigf(acc[mi][j]+xz[mi][j]+b[j]);
        o[j] = ((1.f-z)*nn[mi][j] + z*cs[mi][j])*hm;
      }
      __builtin_nontemporal_store(o, (f4_*)(hout + (size_t)(m0+mi)*H_ + n0));
    }
  }
}

// ---------------- output heads: mu = root@mu_w^T+mu_b ; lv = root@lv_w^T+lv_b
__global__ __launch_bounds__(256)
void head_kernel(const float* __restrict__ root,
                 const float* __restrict__ mu_w, const float* __restrict__ mu_b,
                 const float* __restrict__ lv_w, const float* __restrict__ lv_b,
                 float* __restrict__ out)
{
  __shared__ float rs[32][PAD];
  const int tid = threadIdx.x;
  const int r0 = blockIdx.x*32;
#pragma unroll
  for (int i=0;i<8;++i){
    int q = i*256+tid;
    int m=q>>6, kq=q&63;
    *(float4*)&rs[m][4*kq] = *(const float4*)(root + (size_t)(r0+m)*H_ + 4*kq);
  }
  __syncthreads();
  const float* W; float bias; float* ob;
  if (tid<128){ W = mu_w + tid*H_; bias = mu_b[tid]; ob = out + tid; }
  else        { W = lv_w + (tid-128)*H_; bias = lv_b[tid-128]; ob = out + (size_t)B_*128 + (tid-128); }
  float acc[32];
#pragma unroll
  for (int m=0;m<32;++m) acc[m]=0.f;
  for (int k0=0;k0<H_;k0+=8){
    float4 w0=*(const float4*)(W+k0), w1=*(const float4*)(W+k0+4);
#pragma unroll
    for (int m=0;m<32;++m){
      float4 x0=*(const float4*)&rs[m][k0], x1=*(const float4*)&rs[m][k0+4];
      acc[m] += x0.x*w0.x + x0.y*w0.y + x0.z*w0.z + x0.w*w0.w
              + x1.x*w1.x + x1.y*w1.y + x1.z*w1.z + x1.w*w1.w;
    }
  }
#pragma unroll
  for (int m=0;m<32;++m) ob[(size_t)(r0+m)*128] = acc[m] + bias;
}

extern "C" void kernel_launch(void* const* d_in, const int* in_sizes, int n_in,
                              void* d_out, int out_size, void* d_ws, size_t ws_size,
                              hipStream_t stream)
{
  (void)in_sizes; (void)n_in; (void)out_size; (void)d_ws; (void)ws_size;
  const float* targets = (const float*)d_in[0];
  const float* mask    = (const float*)d_in[1];
  const float* wir_w = (const float*)d_in[2];
  const float* wir_b = (const float*)d_in[3];
  const float* whr_w = (const float*)d_in[4];
  const float* whr_b = (const float*)d_in[5];
  const float* wiz_w = (const float*)d_in[6];
  const float* wiz_b = (const float*)d_in[7];
  const float* whz_w = (const float*)d_in[8];
  const float* whz_b = (const float*)d_in[9];
  const float* win_w = (const float*)d_in[10];
  const float* win_b = (const float*)d_in[11];
  const float* whn_w = (const float*)d_in[12];
  const float* whn_b = (const float*)d_in[13];
  const float* wms_w = (const float*)d_in[14];
  const float* wms_b = (const float*)d_in[15];
  const float* w_w   = (const float*)d_in[16];
  const float* w_b   = (const float*)d_in[17];
  const float* wa_w  = (const float*)d_in[18];
  const float* wa_b  = (const float*)d_in[19];
  const float* mu_w  = (const float*)d_in[20];
  const float* mu_b  = (const float*)d_in[21];
  const float* lv_w  = (const float*)d_in[22];
  const float* lv_b  = (const float*)d_in[23];
  float* out = (float*)d_out;

  float* buf;
  hipGetSymbolAddress((void**)&buf, HIP_SYMBOL(g_hid));   // host-side query, graph-capture safe

  // level d=5 with fused leaf children (start=31, 32 nodes -> slots 0..31, S=1)
  level_kernel<true><<<32*B_/TM, NTHR, 0, stream>>>(targets, mask, buf, 1,
      wir_w, wir_b, whr_w, whr_b, wiz_w, wiz_b, whz_w, whz_b,
      win_w, win_b, whn_w, whn_b, wms_w, wms_b, w_w, w_b, wa_w, wa_b, 31);

  // levels d=4..0: S = 2^(5-d); in-place contraction, root lands at slot 0
  for (int d=4; d>=0; --d){
    int S = 1 << (5-d);
    level_kernel<false><<<((1<<d)*B_)/TM, NTHR, 0, stream>>>(targets, mask, buf, S,
        wir_w, wir_b, whr_w, whr_b, wiz_w, wiz_b, whz_w, whz_b,
        win_w, win_b, whn_w, whn_b, wms_w, wms_b, w_w, w_b, wa_w, wa_b,
        (1<<d)-1);
  }

  head_kernel<<<B_/32, 256, 0, stream>>>(buf, mu_w, mu_b, lv_w, lv_b, out);
}

// Round 8
// 12082.541 us; speedup vs baseline: 1.6998x; 1.3548x over previous
//
#include <hip/hip_runtime.h>
#include <hip/hip_bf16.h>

#define B_ 4096
#define H_ 256
#define I_ 32
#define TM 32     // rows per block; wave w owns rows 4w..4w+3, lane owns 4 cols
#define NTHR 512
#define PAD 260

typedef float f4_ __attribute__((ext_vector_type(4)));

// Static inter-level hidden buffer: 32 slots of (B x H) fp32 = 128 MiB.
// In-place binary-tree contraction: level-d node j occupies slot j*2^(5-d).
__device__ float g_hid[(size_t)32 * B_ * H_];

__device__ __forceinline__ float sigf(float x){ return 1.0f/(1.0f+__expf(-x)); }

// LDS: Xs (rotating X: c0->c1->g->s->cs, rows wave-private) + 16-deep double-buffered
// weight chunks + x tiles. 73 KB -> 2 blocks/CU.
struct SM {
  float Xs[TM][PAD];
  float Wb[2][16][PAD];
  float xsm[TM][I_];
  float xbuf[TM][I_];
};

// out[32x256] = X(32 x K) @ W(256 x K)^T. Per-thread: 4 rows x 4 cols.
// Identical staging structure to the round-6 (passing) kernel: chunk c+1 is
// global-prefetched to regs right after the barrier; ds_write at iter end.
template<int K, int XS>
__device__ __forceinline__ void gemm32(const float* __restrict__ W,
                                       const float* __restrict__ X,   // LDS
                                       float (*Wb)[16][PAD],
                                       int tid, int m0, int n0,
                                       f4_ acc[4])
{
  constexpr int NC = K/16;
#pragma unroll
  for (int mi=0;mi<4;++mi) acc[mi] = (f4_)0.f;

  const int i0 = tid, i1 = NTHR + tid;
  const int na = i0>>2, ja = i0&3, nb = i1>>2, jb = i1&3;
  f4_ pre0, pre1;
  pre0 = *(const f4_*)(W + (size_t)na*K + 4*ja);
  pre1 = *(const f4_*)(W + (size_t)nb*K + 4*jb);
  __syncthreads();                    // prior Wb readers done
  Wb[0][4*ja+0][na]=pre0.x; Wb[0][4*ja+1][na]=pre0.y;
  Wb[0][4*ja+2][na]=pre0.z; Wb[0][4*ja+3][na]=pre0.w;
  Wb[0][4*jb+0][nb]=pre1.x; Wb[0][4*jb+1][nb]=pre1.y;
  Wb[0][4*jb+2][nb]=pre1.z; Wb[0][4*jb+3][nb]=pre1.w;

  for (int c=0;c<NC;++c){
    __syncthreads();                  // Wb[c&1] visible to all waves
    const int kb = c*16;
    if (c+1<NC){
      pre0 = *(const f4_*)(W + (size_t)na*K + kb+16 + 4*ja);
      pre1 = *(const f4_*)(W + (size_t)nb*K + kb+16 + 4*jb);
    }
    const int b = c&1;
#pragma unroll
    for (int ku=0;ku<4;++ku){
      f4_ wv0 = *(const f4_*)&Wb[b][4*ku+0][n0];
      f4_ wv1 = *(const f4_*)&Wb[b][4*ku+1][n0];
      f4_ wv2 = *(const f4_*)&Wb[b][4*ku+2][n0];
      f4_ wv3 = *(const f4_*)&Wb[b][4*ku+3][n0];
#pragma unroll
      for (int mi=0;mi<4;++mi){
        f4_ xv = *(const f4_*)(X + (m0+mi)*XS + kb + 4*ku);  // wave-uniform broadcast
        acc[mi] += xv.x*wv0 + xv.y*wv1 + xv.z*wv2 + xv.w*wv3;
      }
    }
    if (c+1<NC){
      const int b2=(c+1)&1;
      Wb[b2][4*ja+0][na]=pre0.x; Wb[b2][4*ja+1][na]=pre0.y;
      Wb[b2][4*ja+2][na]=pre0.z; Wb[b2][4*ja+3][na]=pre0.w;
      Wb[b2][4*jb+0][nb]=pre1.x; Wb[b2][4*jb+1][nb]=pre1.y;
      Wb[b2][4*jb+2][nb]=pre1.z; Wb[b2][4*jb+3][nb]=pre1.w;
    }
  }
}

// ---------------- fused level kernel (in-place slot contraction) ----------------
template<bool FUSE_LEAF>
__global__ __launch_bounds__(NTHR, 2)
void level_kernel(const float* __restrict__ targets, const float* __restrict__ mask,
                  float* __restrict__ buf, int S,    // node j: slot j*S ; children at j*S, j*S+S/2
                  const float* __restrict__ wir_w, const float* __restrict__ wir_b,
                  const float* __restrict__ whr_w, const float* __restrict__ whr_b,
                  const float* __restrict__ wiz_w, const float* __restrict__ wiz_b,
                  const float* __restrict__ whz_w, const float* __restrict__ whz_b,
                  const float* __restrict__ win_w, const float* __restrict__ win_b,
                  const float* __restrict__ whn_w, const float* __restrict__ whn_b,
                  const float* __restrict__ wms_w, const float* __restrict__ wms_b,
                  const float* __restrict__ w_w,  const float* __restrict__ w_b,
                  const float* __restrict__ wa_w, const float* __restrict__ wa_b,
                  int start)
{
  __shared__ SM sm;
  const int tid  = threadIdx.x;
  const int w    = tid >> 6, lane = tid & 63;
  const int m0   = w*4, n0 = lane*4;
  const long gr0 = (long)blockIdx.x * TM;
  const int node = (int)(gr0 / B_);
  const int b0   = (int)(gr0 % B_);
  const size_t slot = (size_t)node * S * B_ * H_;
  float* hout = buf + slot + (size_t)b0 * H_;
  const int xr_row = m0 + ((lane&31)>>3), xr_q = 4*(lane & 7);  // wave-private x map (lanes 0..31)

  // stage parent x (wave-private rows -> no barrier needed before next gemm's internal barriers)
  if (lane < 32){
    const float* xg = targets + ((size_t)(start+node)*B_ + b0)*I_;
    *(f4_*)&sm.xsm[xr_row][xr_q] =
      __builtin_nontemporal_load((const f4_*)(xg + (size_t)xr_row*I_ + xr_q));
  }

  f4_ acc[4], rc0[4], ss[4], xr[4];
  float s0[4], s1[4];

  // ---- child 0 -> Xs + rc0 ----
  if (FUSE_LEAF){
    if (lane < 32){
      const float* x0g = targets + ((size_t)(63+2*node)*B_ + b0)*I_;
      *(f4_*)&sm.xbuf[xr_row][xr_q] =
        __builtin_nontemporal_load((const f4_*)(x0g + (size_t)xr_row*I_ + xr_q));
    }
    f4_ za[4];
    gemm32<I_, I_>(wiz_w, &sm.xbuf[0][0], sm.Wb, tid, m0, n0, za);
    gemm32<I_, I_>(win_w, &sm.xbuf[0][0], sm.Wb, tid, m0, n0, acc);
    f4_ bz1=*(const f4_*)(wiz_b+n0), bz2=*(const f4_*)(whz_b+n0);
    f4_ bn1=*(const f4_*)(win_b+n0), bn2=*(const f4_*)(whn_b+n0);
    const float* mk = mask + (size_t)(63+2*node)*B_ + b0;
#pragma unroll
    for (int mi=0;mi<4;++mi){
      float hm = mk[m0+mi];
      f4_ v;
#pragma unroll
      for (int j=0;j<4;++j){
        float z  = sigf(za[mi][j]+bz1[j]+bz2[j]);
        float nn = tanhf(acc[mi][j]+bn1[j]+bn2[j]);
        v[j] = (1.f-z)*nn*hm;
      }
      rc0[mi]=v; *(f4_*)&sm.Xs[m0+mi][n0]=v;
    }
  } else {
    const float* c0g = buf + slot + (size_t)b0 * H_;
#pragma unroll
    for (int mi=0;mi<4;++mi){
      f4_ v = __builtin_nontemporal_load((const f4_*)(c0g + (size_t)(m0+mi)*H_ + n0));
      rc0[mi]=v; *(f4_*)&sm.Xs[m0+mi][n0]=v;
    }
  }

  // ---- ms0 -> s0 ----
  gemm32<H_, PAD>(wms_w, &sm.Xs[0][0], sm.Wb, tid, m0, n0, acc);
  {
    f4_ b=*(const f4_*)(wms_b+n0), ww=*(const f4_*)(w_w+n0);
    float wb0 = w_b[0];
#pragma unroll
    for (int mi=0;mi<4;++mi){
      float p = tanhf(acc[mi][0]+b[0])*ww[0] + tanhf(acc[mi][1]+b[1])*ww[1]
              + tanhf(acc[mi][2]+b[2])*ww[2] + tanhf(acc[mi][3]+b[3])*ww[3];
#pragma unroll
      for (int off=32; off>0; off>>=1) p += __shfl_xor(p, off);
      s0[mi] = p + wb0;
    }
  }

  // ---- xr ----
  gemm32<I_, I_>(wir_w, &sm.xsm[0][0], sm.Wb, tid, m0, n0, xr);
  { f4_ b=*(const f4_*)(wir_b+n0);
#pragma unroll
    for (int mi=0;mi<4;++mi) xr[mi] += b; }

  // ---- r0 ; ss = r0*c0 ----
  gemm32<H_, PAD>(whr_w, &sm.Xs[0][0], sm.Wb, tid, m0, n0, acc);
  { f4_ b=*(const f4_*)(whr_b+n0);
#pragma unroll
    for (int mi=0;mi<4;++mi){
      f4_ r;
#pragma unroll
      for (int j=0;j<4;++j) r[j] = sigf(acc[mi][j]+xr[mi][j]+b[j]);
      ss[mi] = r*rc0[mi];
    }
  }

  // ---- child 1 -> Xs (rows wave-private; in-wave read-before-write ordering is safe) ----
  if (FUSE_LEAF){
    if (lane < 32){
      const float* x1g = targets + ((size_t)(64+2*node)*B_ + b0)*I_;
      *(f4_*)&sm.xbuf[xr_row][xr_q] =
        __builtin_nontemporal_load((const f4_*)(x1g + (size_t)xr_row*I_ + xr_q));
    }
    f4_ za[4];
    gemm32<I_, I_>(wiz_w, &sm.xbuf[0][0], sm.Wb, tid, m0, n0, za);
    gemm32<I_, I_>(win_w, &sm.xbuf[0][0], sm.Wb, tid, m0, n0, acc);
    f4_ bz1=*(const f4_*)(wiz_b+n0), bz2=*(const f4_*)(whz_b+n0);
    f4_ bn1=*(const f4_*)(win_b+n0), bn2=*(const f4_*)(whn_b+n0);
    const float* mk = mask + (size_t)(64+2*node)*B_ + b0;
#pragma unroll
    for (int mi=0;mi<4;++mi){
      float hm = mk[m0+mi];
      f4_ v;
#pragma unroll
      for (int j=0;j<4;++j){
        float z  = sigf(za[mi][j]+bz1[j]+bz2[j]);
        float nn = tanhf(acc[mi][j]+bn1[j]+bn2[j]);
        v[j] = (1.f-z)*nn*hm;
      }
      *(f4_*)&sm.Xs[m0+mi][n0]=v;
    }
  } else {
    const float* c1g = buf + slot + (size_t)(S>>1)*B_*H_ + (size_t)b0*H_;
#pragma unroll
    for (int mi=0;mi<4;++mi)
      *(f4_*)&sm.Xs[m0+mi][n0] =
        __builtin_nontemporal_load((const f4_*)(c1g + (size_t)(m0+mi)*H_ + n0));
  }

  // ---- ms1 -> s1 ----
  gemm32<H_, PAD>(wms_w + H_*H_, &sm.Xs[0][0], sm.Wb, tid, m0, n0, acc);
  {
    f4_ b=*(const f4_*)(wms_b+H_+n0), ww=*(const f4_*)(w_w+n0);
    float wb0 = w_b[0];
#pragma unroll
    for (int mi=0;mi<4;++mi){
      float p = tanhf(acc[mi][0]+b[0])*ww[0] + tanhf(acc[mi][1]+b[1])*ww[1]
              + tanhf(acc[mi][2]+b[2])*ww[2] + tanhf(acc[mi][3]+b[3])*ww[3];
#pragma unroll
      for (int off=32; off>0; off>>=1) p += __shfl_xor(p, off);
      s1[mi] = p + wb0;
    }
  }

  // ---- r1 ; ss += r1*c1 ; g = a0*c0 + a1*c1 -> Xs ----
  gemm32<H_, PAD>(whr_w, &sm.Xs[0][0], sm.Wb, tid, m0, n0, acc);
  { f4_ b=*(const f4_*)(whr_b+n0);
#pragma unroll
    for (int mi=0;mi<4;++mi){
      f4_ c1t = *(const f4_*)&sm.Xs[m0+mi][n0];   // Xs still holds c1
      f4_ r;
#pragma unroll
      for (int j=0;j<4;++j) r[j] = sigf(acc[mi][j]+xr[mi][j]+b[j]);
      ss[mi] += r*c1t;
      float sum = s0[mi]+s1[mi];
      float a0 = s0[mi]/sum, a1 = s1[mi]/sum;
      *(f4_*)&sm.Xs[m0+mi][n0] = a0*rc0[mi] + a1*c1t;   // g
    }
  }

  // ---- child_sum = tanh(g@wa^T + b) ; then Xs <- s ----
  f4_ cs[4];
  gemm32<H_, PAD>(wa_w, &sm.Xs[0][0], sm.Wb, tid, m0, n0, acc);
  { f4_ b=*(const f4_*)(wa_b+n0);
#pragma unroll
    for (int mi=0;mi<4;++mi){
#pragma unroll
      for (int j=0;j<4;++j) cs[mi][j] = tanhf(acc[mi][j]+b[j]);
      *(f4_*)&sm.Xs[m0+mi][n0] = ss[mi];
    }
  }

  // ---- xn ; n = tanh(xn + s@whn^T + b) ; then Xs <- child_sum ----
  f4_ xn[4];
  gemm32<I_, I_>(win_w, &sm.xsm[0][0], sm.Wb, tid, m0, n0, xn);
  { f4_ b=*(const f4_*)(win_b+n0);
#pragma unroll
    for (int mi=0;mi<4;++mi) xn[mi] += b; }
  f4_ nn[4];
  gemm32<H_, PAD>(whn_w, &sm.Xs[0][0], sm.Wb, tid, m0, n0, acc);
  { f4_ b=*(const f4_*)(whn_b+n0);
#pragma unroll
    for (int mi=0;mi<4;++mi){
#pragma unroll
      for (int j=0;j<4;++j) nn[mi][j] = tanhf(acc[mi][j]+xn[mi][j]+b[j]);
      *(f4_*)&sm.Xs[m0+mi][n0] = cs[mi];
    }
  }

  // ---- xz ; z ; h = (1-z)*n + z*cs ; store h*mask ----
  f4_ xz[4];
  gemm32<I_, I_>(wiz_w, &sm.xsm[0][0], sm.Wb, tid, m0, n0, xz);
  { f4_ b=*(const f4_*)(wiz_b+n0);
#pragma unroll
    for (int mi=0;mi<4;++mi) xz[mi] += b; }
  gemm32<H_, PAD>(whz_w, &sm.Xs[0][0], sm.Wb, tid, m0, n0, acc);
  {
    f4_ b=*(const f4_*)(whz_b+n0);
    const float* mk = mask + (size_t)(start+node)*B_ + b0;
#pragma unroll
    for (int mi=0;mi<4;++mi){
      float hm = mk[m0+mi];
      f4_ o;
#pragma unroll
      for (int j=0;j<4;++j){
        float z = sigf(acc[mi][j]+xz[mi][j]+b[j]);
        o[j] = ((1.f-z)*nn[mi][j] + z*cs[mi][j])*hm;
      }
      __builtin_nontemporal_store(o, (f4_*)(hout + (size_t)(m0+mi)*H_ + n0));
    }
  }
}

// ---------------- output heads: mu = root@mu_w^T+mu_b ; lv = root@lv_w^T+lv_b
__global__ __launch_bounds__(256)
void head_kernel(const float* __restrict__ root,
                 const float* __restrict__ mu_w, const float* __restrict__ mu_b,
                 const float* __restrict__ lv_w, const float* __restrict__ lv_b,
                 float* __restrict__ out)
{
  __shared__ float rs[32][260];
  const int tid = threadIdx.x;
  const int r0 = blockIdx.x*32;
#pragma unroll
  for (int i=0;i<8;++i){
    int q = i*256+tid;
    int m=q>>6, kq=q&63;
    *(float4*)&rs[m][4*kq] = *(const float4*)(root + (size_t)(r0+m)*H_ + 4*kq);
  }
  __syncthreads();
  const float* W; float bias; float* ob;
  if (tid<128){ W = mu_w + tid*H_; bias = mu_b[tid]; ob = out + tid; }
  else        { W = lv_w + (tid-128)*H_; bias = lv_b[tid-128]; ob = out + (size_t)B_*128 + (tid-128); }
  float acc[32];
#pragma unroll
  for (int m=0;m<32;++m) acc[m]=0.f;
  for (int k0=0;k0<H_;k0+=8){
    float4 w0=*(const float4*)(W+k0), w1=*(const float4*)(W+k0+4);
#pragma unroll
    for (int m=0;m<32;++m){
      float4 x0=*(const float4*)&rs[m][k0], x1=*(const float4*)&rs[m][k0+4];
      acc[m] += x0.x*w0.x + x0.y*w0.y + x0.z*w0.z + x0.w*w0.w
              + x1.x*w1.x + x1.y*w1.y + x1.z*w1.z + x1.w*w1.w;
    }
  }
#pragma unroll
  for (int m=0;m<32;++m) ob[(size_t)(r0+m)*128] = acc[m] + bias;
}

extern "C" void kernel_launch(void* const* d_in, const int* in_sizes, int n_in,
                              void* d_out, int out_size, void* d_ws, size_t ws_size,
                              hipStream_t stream)
{
  (void)in_sizes; (void)n_in; (void)out_size; (void)d_ws; (void)ws_size;
  const float* targets = (const float*)d_in[0];
  const float* mask    = (const float*)d_in[1];
  const float* wir_w = (const float*)d_in[2];
  const float* wir_b = (const float*)d_in[3];
  const float* whr_w = (const float*)d_in[4];
  const float* whr_b = (const float*)d_in[5];
  const float* wiz_w = (const float*)d_in[6];
  const float* wiz_b = (const float*)d_in[7];
  const float* whz_w = (const float*)d_in[8];
  const float* whz_b = (const float*)d_in[9];
  const float* win_w = (const float*)d_in[10];
  const float* win_b = (const float*)d_in[11];
  const float* whn_w = (const float*)d_in[12];
  const float* whn_b = (const float*)d_in[13];
  const float* wms_w = (const float*)d_in[14];
  const float* wms_b = (const float*)d_in[15];
  const float* w_w   = (const float*)d_in[16];
  const float* w_b   = (const float*)d_in[17];
  const float* wa_w  = (const float*)d_in[18];
  const float* wa_b  = (const float*)d_in[19];
  const float* mu_w  = (const float*)d_in[20];
  const float* mu_b  = (const float*)d_in[21];
  const float* lv_w  = (const float*)d_in[22];
  const float* lv_b  = (const float*)d_in[23];
  float* out = (float*)d_out;

  float* buf;
  hipGetSymbolAddress((void**)&buf, HIP_SYMBOL(g_hid));   // host-side query, graph-capture safe

  // level d=5 with fused leaf children (start=31, 32 nodes -> slots 0..31, S=1)
  level_kernel<true><<<32*B_/TM, NTHR, 0, stream>>>(targets, mask, buf, 1,
      wir_w, wir_b, whr_w, whr_b, wiz_w, wiz_b, whz_w, whz_b,
      win_w, win_b, whn_w, whn_b, wms_w, wms_b, w_w, w_b, wa_w, wa_b, 31);

  // levels d=4..0: S = 2^(5-d); in-place contraction, root lands at slot 0
  for (int d=4; d>=0; --d){
    int S = 1 << (5-d);
    level_kernel<false><<<((1<<d)*B_)/TM, NTHR, 0, stream>>>(targets, mask, buf, S,
        wir_w, wir_b, whr_w, whr_b, wiz_w, wiz_b, whz_w, whz_b,
        win_w, win_b, whn_w, whn_b, wms_w, wms_b, w_w, w_b, wa_w, wa_b,
        (1<<d)-1);
  }

  head_kernel<<<B_/32, 256, 0, stream>>>(buf, mu_w, mu_b, lv_w, lv_b, out);
}

// Round 9
// 11500.392 us; speedup vs baseline: 1.7858x; 1.0506x over previous
//
#include <hip/hip_runtime.h>
#include <hip/hip_bf16.h>

#define B_ 4096
#define H_ 256
#define I_ 32
#define TM 32     // rows per block; wave w owns rows 4w..4w+3, lane owns 4 cols
#define NTHR 512
#define PAD 260

typedef float f4_ __attribute__((ext_vector_type(4)));

// Static inter-level hidden buffer: 32 slots of (B x H) fp32 = 128 MiB.
// In-place binary-tree contraction: level-d node j occupies slot j*2^(5-d).
__device__ float g_hid[(size_t)32 * B_ * H_];

__device__ __forceinline__ float sigf(float x){ return 1.0f/(1.0f+__expf(-x)); }

// ---- GEMM as a macro: NO array locals, NO array params -> nothing can fall to
// scratch (r8 post-mortem: f4_ acc[4] passed by pointer defeated SROA; every
// acc update was a scratch round-trip => ~11.7 GB HBM writes per d=5 dispatch).
// Computes acc0..acc3 = X(rows m0..m0+3 of 2D __shared__ XA) @ W(256 x K)^T
// at cols n0..n0+3. Same staging/barrier structure as the passing r8 kernel:
// chunk c+1 global-prefetched to named regs after the barrier, ds_write at end.
#define GEMM(WP, XA, K) do{                                                    \
  constexpr int NC=(K)/16;                                                     \
  acc0=(f4_)0.f; acc1=(f4_)0.f; acc2=(f4_)0.f; acc3=(f4_)0.f;                  \
  const float* Wq=(WP);                                                        \
  f4_ p0=*(const f4_*)(Wq+(size_t)na*(K)+4*ja);                                \
  f4_ p1=*(const f4_*)(Wq+(size_t)nb*(K)+4*ja);                                \
  __syncthreads();                    /* prior Wb readers done */              \
  Wb[0][4*ja+0][na]=p0.x; Wb[0][4*ja+1][na]=p0.y;                              \
  Wb[0][4*ja+2][na]=p0.z; Wb[0][4*ja+3][na]=p0.w;                              \
  Wb[0][4*ja+0][nb]=p1.x; Wb[0][4*ja+1][nb]=p1.y;                              \
  Wb[0][4*ja+2][nb]=p1.z; Wb[0][4*ja+3][nb]=p1.w;                              \
  for(int c=0;c<NC;++c){                                                       \
    __syncthreads();                  /* Wb[c&1] visible to all waves */       \
    const int kb=c*16;                                                         \
    if(c+1<NC){                                                                \
      p0=*(const f4_*)(Wq+(size_t)na*(K)+kb+16+4*ja);                          \
      p1=*(const f4_*)(Wq+(size_t)nb*(K)+kb+16+4*ja);                          \
    }                                                                          \
    const int wsel=c&1;                                                        \
    _Pragma("unroll")                                                          \
    for(int ku=0;ku<4;++ku){                                                   \
      f4_ wv0=*(const f4_*)&Wb[wsel][4*ku+0][n0];                              \
      f4_ wv1=*(const f4_*)&Wb[wsel][4*ku+1][n0];                              \
      f4_ wv2=*(const f4_*)&Wb[wsel][4*ku+2][n0];                              \
      f4_ wv3=*(const f4_*)&Wb[wsel][4*ku+3][n0];                              \
      f4_ xv;                                                                  \
      xv=*(const f4_*)&XA[m0+0][kb+4*ku]; acc0+=xv.x*wv0+xv.y*wv1+xv.z*wv2+xv.w*wv3; \
      xv=*(const f4_*)&XA[m0+1][kb+4*ku]; acc1+=xv.x*wv0+xv.y*wv1+xv.z*wv2+xv.w*wv3; \
      xv=*(const f4_*)&XA[m0+2][kb+4*ku]; acc2+=xv.x*wv0+xv.y*wv1+xv.z*wv2+xv.w*wv3; \
      xv=*(const f4_*)&XA[m0+3][kb+4*ku]; acc3+=xv.x*wv0+xv.y*wv1+xv.z*wv2+xv.w*wv3; \
    }                                                                          \
    if(c+1<NC){                                                                \
      const int b2=(c+1)&1;                                                    \
      Wb[b2][4*ja+0][na]=p0.x; Wb[b2][4*ja+1][na]=p0.y;                        \
      Wb[b2][4*ja+2][na]=p0.z; Wb[b2][4*ja+3][na]=p0.w;                        \
      Wb[b2][4*ja+0][nb]=p1.x; Wb[b2][4*ja+1][nb]=p1.y;                        \
      Wb[b2][4*ja+2][nb]=p1.z; Wb[b2][4*ja+3][nb]=p1.w;                        \
    }                                                                          \
  }                                                                            \
}while(0)

#define ROWS(F) F(0) F(1) F(2) F(3)

// ---------------- fused level kernel (in-place slot contraction) ----------------
template<bool FUSE_LEAF>
__global__ __launch_bounds__(NTHR, 2)
void level_kernel(const float* __restrict__ targets, const float* __restrict__ mask,
                  float* __restrict__ buf, int S,    // node j: slot j*S ; children at j*S, j*S+S/2
                  const float* __restrict__ wir_w, const float* __restrict__ wir_b,
                  const float* __restrict__ whr_w, const float* __restrict__ whr_b,
                  const float* __restrict__ wiz_w, const float* __restrict__ wiz_b,
                  const float* __restrict__ whz_w, const float* __restrict__ whz_b,
                  const float* __restrict__ win_w, const float* __restrict__ win_b,
                  const float* __restrict__ whn_w, const float* __restrict__ whn_b,
                  const float* __restrict__ wms_w, const float* __restrict__ wms_b,
                  const float* __restrict__ w_w,  const float* __restrict__ w_b,
                  const float* __restrict__ wa_w, const float* __restrict__ wa_b,
                  int start)
{
  __shared__ float Xs[TM][PAD];      // rotating X: c0 -> c1 -> g -> s -> cs (rows wave-private)
  __shared__ float Wb[2][16][PAD];   // double-buffered weight k-chunks [k][n]
  __shared__ float xsm[TM][I_];      // parent x
  __shared__ float xbuf[TM][I_];     // leaf-child x scratch

  const int tid=threadIdx.x;
  const int w=tid>>6, lane=tid&63;
  const int m0=w*4, n0=lane*4;
  const int na=tid>>2, ja=tid&3, nb=128+(tid>>2);   // W staging map (jb==ja)
  const long gr0=(long)blockIdx.x*TM;
  const int node=(int)(gr0/B_), b0=(int)(gr0%B_);
  const size_t slot=(size_t)node*S*B_*H_;
  float* hout=buf+slot+(size_t)b0*H_;
  const int xrow=m0+((lane&31)>>3), xq=4*(lane&7);  // wave-private x map (lanes 0..31)

  if (lane<32){
    const float* xg=targets+((size_t)(start+node)*B_+b0)*I_;
    *(f4_*)&xsm[xrow][xq]=__builtin_nontemporal_load((const f4_*)(xg+(size_t)xrow*I_+xq));
  }

  f4_ acc0,acc1,acc2,acc3;
  f4_ rc00,rc01,rc02,rc03;
  f4_ ss0,ss1,ss2,ss3;            // ss; later reused as xz
  f4_ xr0,xr1,xr2,xr3;            // xr; later reused as xn
  f4_ cs0,cs1,cs2,cs3, nn0,nn1,nn2,nn3;
  float s00,s01,s02,s03, s10,s11,s12,s13;

  // ---- child 0 -> Xs + rc0 ----
  if (FUSE_LEAF){
    if (lane<32){
      const float* x0g=targets+((size_t)(63+2*node)*B_+b0)*I_;
      *(f4_*)&xbuf[xrow][xq]=__builtin_nontemporal_load((const f4_*)(x0g+(size_t)xrow*I_+xq));
    }
    GEMM(wiz_w, xbuf, I_);
    f4_ za0=acc0, za1=acc1, za2=acc2, za3=acc3;
    GEMM(win_w, xbuf, I_);
    f4_ bzs=*(const f4_*)(wiz_b+n0)+*(const f4_*)(whz_b+n0);
    f4_ bns=*(const f4_*)(win_b+n0)+*(const f4_*)(whn_b+n0);
    const float* mkp=mask+(size_t)(63+2*node)*B_+b0;
#define LEAF0(r) { float hm=mkp[m0+r]; f4_ v;                                   \
    v[0]=(1.f-sigf(za##r[0]+bzs[0]))*tanhf(acc##r[0]+bns[0])*hm;                \
    v[1]=(1.f-sigf(za##r[1]+bzs[1]))*tanhf(acc##r[1]+bns[1])*hm;                \
    v[2]=(1.f-sigf(za##r[2]+bzs[2]))*tanhf(acc##r[2]+bns[2])*hm;                \
    v[3]=(1.f-sigf(za##r[3]+bzs[3]))*tanhf(acc##r[3]+bns[3])*hm;                \
    rc0##r=v; *(f4_*)&Xs[m0+r][n0]=v; }
    ROWS(LEAF0)
  } else {
    const float* c0g=buf+slot+(size_t)b0*H_;
#define LD0(r) { f4_ v=__builtin_nontemporal_load((const f4_*)(c0g+(size_t)(m0+r)*H_+n0)); \
    rc0##r=v; *(f4_*)&Xs[m0+r][n0]=v; }
    ROWS(LD0)
  }

  // ---- ms0 -> s0 ----
  GEMM(wms_w, Xs, H_);
  {
    f4_ bm=*(const f4_*)(wms_b+n0), ww=*(const f4_*)(w_w+n0);
    float wb0=w_b[0];
#define MS(r, sdst) { float p=tanhf(acc##r[0]+bm[0])*ww[0]+tanhf(acc##r[1]+bm[1])*ww[1] \
                             +tanhf(acc##r[2]+bm[2])*ww[2]+tanhf(acc##r[3]+bm[3])*ww[3]; \
    p+=__shfl_xor(p,32); p+=__shfl_xor(p,16); p+=__shfl_xor(p,8);               \
    p+=__shfl_xor(p,4);  p+=__shfl_xor(p,2);  p+=__shfl_xor(p,1);               \
    sdst=p+wb0; }
    MS(0,s00) MS(1,s01) MS(2,s02) MS(3,s03)
  }

  // ---- xr ----
  GEMM(wir_w, xsm, I_);
  { f4_ bv=*(const f4_*)(wir_b+n0); xr0=acc0+bv; xr1=acc1+bv; xr2=acc2+bv; xr3=acc3+bv; }

  // ---- r0 ; ss = r0*c0 ----
  GEMM(whr_w, Xs, H_);
  {
    f4_ bv=*(const f4_*)(whr_b+n0);
#define R0(r) { f4_ rv;                                                         \
    rv[0]=sigf(acc##r[0]+xr##r[0]+bv[0]); rv[1]=sigf(acc##r[1]+xr##r[1]+bv[1]); \
    rv[2]=sigf(acc##r[2]+xr##r[2]+bv[2]); rv[3]=sigf(acc##r[3]+xr##r[3]+bv[3]); \
    ss##r=rv*rc0##r; }
    ROWS(R0)
  }

  // ---- child 1 -> Xs (rows wave-private; in-wave read-before-write is safe) ----
  if (FUSE_LEAF){
    if (lane<32){
      const float* x1g=targets+((size_t)(64+2*node)*B_+b0)*I_;
      *(f4_*)&xbuf[xrow][xq]=__builtin_nontemporal_load((const f4_*)(x1g+(size_t)xrow*I_+xq));
    }
    GEMM(wiz_w, xbuf, I_);
    f4_ za0=acc0, za1=acc1, za2=acc2, za3=acc3;
    GEMM(win_w, xbuf, I_);
    f4_ bzs=*(const f4_*)(wiz_b+n0)+*(const f4_*)(whz_b+n0);
    f4_ bns=*(const f4_*)(win_b+n0)+*(const f4_*)(whn_b+n0);
    const float* mkp=mask+(size_t)(64+2*node)*B_+b0;
#define LEAF1(r) { float hm=mkp[m0+r]; f4_ v;                                   \
    v[0]=(1.f-sigf(za##r[0]+bzs[0]))*tanhf(acc##r[0]+bns[0])*hm;                \
    v[1]=(1.f-sigf(za##r[1]+bzs[1]))*tanhf(acc##r[1]+bns[1])*hm;                \
    v[2]=(1.f-sigf(za##r[2]+bzs[2]))*tanhf(acc##r[2]+bns[2])*hm;                \
    v[3]=(1.f-sigf(za##r[3]+bzs[3]))*tanhf(acc##r[3]+bns[3])*hm;                \
    *(f4_*)&Xs[m0+r][n0]=v; }
    ROWS(LEAF1)
  } else {
    const float* c1g=buf+slot+(size_t)(S>>1)*B_*H_+(size_t)b0*H_;
#define LD1(r) { f4_ v=__builtin_nontemporal_load((const f4_*)(c1g+(size_t)(m0+r)*H_+n0)); \
    *(f4_*)&Xs[m0+r][n0]=v; }
    ROWS(LD1)
  }

  // ---- ms1 -> s1 ----
  GEMM(wms_w+H_*H_, Xs, H_);
  {
    f4_ bm=*(const f4_*)(wms_b+H_+n0), ww=*(const f4_*)(w_w+n0);
    float wb0=w_b[0];
    MS(0,s10) MS(1,s11) MS(2,s12) MS(3,s13)
  }

  // ---- r1 ; ss += r1*c1 ; g = a0*c0 + a1*c1 -> Xs ----
  GEMM(whr_w, Xs, H_);
  {
    f4_ bv=*(const f4_*)(whr_b+n0);
#define R1(r, sA, sB) { f4_ c1t=*(const f4_*)&Xs[m0+r][n0]; f4_ rv;             \
    rv[0]=sigf(acc##r[0]+xr##r[0]+bv[0]); rv[1]=sigf(acc##r[1]+xr##r[1]+bv[1]); \
    rv[2]=sigf(acc##r[2]+xr##r[2]+bv[2]); rv[3]=sigf(acc##r[3]+xr##r[3]+bv[3]); \
    ss##r+=rv*c1t; float sum=sA+sB; float a0v=sA/sum, a1v=sB/sum;               \
    *(f4_*)&Xs[m0+r][n0]=a0v*rc0##r+a1v*c1t; }
    R1(0,s00,s10) R1(1,s01,s11) R1(2,s02,s12) R1(3,s03,s13)
  }

  // ---- child_sum = tanh(g@wa^T + b) ; then Xs <- ss ----
  GEMM(wa_w, Xs, H_);
  {
    f4_ bv=*(const f4_*)(wa_b+n0);
#define CSX(r) { f4_ v;                                                         \
    v[0]=tanhf(acc##r[0]+bv[0]); v[1]=tanhf(acc##r[1]+bv[1]);                   \
    v[2]=tanhf(acc##r[2]+bv[2]); v[3]=tanhf(acc##r[3]+bv[3]);                   \
    cs##r=v; *(f4_*)&Xs[m0+r][n0]=ss##r; }
    ROWS(CSX)
  }

  // ---- xn (reuses xr regs) ; n = tanh(xn + s@whn^T + b) ; then Xs <- cs ----
  GEMM(win_w, xsm, I_);
  { f4_ bv=*(const f4_*)(win_b+n0); xr0=acc0+bv; xr1=acc1+bv; xr2=acc2+bv; xr3=acc3+bv; }
  GEMM(whn_w, Xs, H_);
  {
    f4_ bv=*(const f4_*)(whn_b+n0);
#define NNX(r) { f4_ v;                                                         \
    v[0]=tanhf(acc##r[0]+xr##r[0]+bv[0]); v[1]=tanhf(acc##r[1]+xr##r[1]+bv[1]); \
    v[2]=tanhf(acc##r[2]+xr##r[2]+bv[2]); v[3]=tanhf(acc##r[3]+xr##r[3]+bv[3]); \
    nn##r=v; *(f4_*)&Xs[m0+r][n0]=cs##r; }
    ROWS(NNX)
  }

  // ---- xz (reuses ss regs) ; z ; h = (1-z)*n + z*cs ; store h*mask ----
  GEMM(wiz_w, xsm, I_);
  { f4_ bv=*(const f4_*)(wiz_b+n0); ss0=acc0+bv; ss1=acc1+bv; ss2=acc2+bv; ss3=acc3+bv; }
  GEMM(whz_w, Xs, H_);
  {
    f4_ bv=*(const f4_*)(whz_b+n0);
    const float* mkp=mask+(size_t)(start+node)*B_+b0;
#define HZ(r) { float hm=mkp[m0+r]; f4_ o; float z;                             \
    z=sigf(acc##r[0]+ss##r[0]+bv[0]); o[0]=((1.f-z)*nn##r[0]+z*cs##r[0])*hm;    \
    z=sigf(acc##r[1]+ss##r[1]+bv[1]); o[1]=((1.f-z)*nn##r[1]+z*cs##r[1])*hm;    \
    z=sigf(acc##r[2]+ss##r[2]+bv[2]); o[2]=((1.f-z)*nn##r[2]+z*cs##r[2])*hm;    \
    z=sigf(acc##r[3]+ss##r[3]+bv[3]); o[3]=((1.f-z)*nn##r[3]+z*cs##r[3])*hm;    \
    __builtin_nontemporal_store(o,(f4_*)(hout+(size_t)(m0+r)*H_+n0)); }
    ROWS(HZ)
  }
}

// ---------------- output heads: mu = root@mu_w^T+mu_b ; lv = root@lv_w^T+lv_b
__global__ __launch_bounds__(256)
void head_kernel(const float* __restrict__ root,
                 const float* __restrict__ mu_w, const float* __restrict__ mu_b,
                 const float* __restrict__ lv_w, const float* __restrict__ lv_b,
                 float* __restrict__ out)
{
  __shared__ float rs[32][260];
  const int tid = threadIdx.x;
  const int r0 = blockIdx.x*32;
#pragma unroll
  for (int i=0;i<8;++i){
    int q = i*256+tid;
    int m=q>>6, kq=q&63;
    *(float4*)&rs[m][4*kq] = *(const float4*)(root + (size_t)(r0+m)*H_ + 4*kq);
  }
  __syncthreads();
  const float* W; float bias; float* ob;
  if (tid<128){ W = mu_w + tid*H_; bias = mu_b[tid]; ob = out + tid; }
  else        { W = lv_w + (tid-128)*H_; bias = lv_b[tid-128]; ob = out + (size_t)B_*128 + (tid-128); }
  float acc[32];
#pragma unroll
  for (int m=0;m<32;++m) acc[m]=0.f;
  for (int k0=0;k0<H_;k0+=8){
    float4 w0=*(const float4*)(W+k0), w1=*(const float4*)(W+k0+4);
#pragma unroll
    for (int m=0;m<32;++m){
      float4 x0=*(const float4*)&rs[m][k0], x1=*(const float4*)&rs[m][k0+4];
      acc[m] += x0.x*w0.x + x0.y*w0.y + x0.z*w0.z + x0.w*w0.w
              + x1.x*w1.x + x1.y*w1.y + x1.z*w1.z + x1.w*w1.w;
    }
  }
#pragma unroll
  for (int m=0;m<32;++m) ob[(size_t)(r0+m)*128] = acc[m] + bias;
}

extern "C" void kernel_launch(void* const* d_in, const int* in_sizes, int n_in,
                              void* d_out, int out_size, void* d_ws, size_t ws_size,
                              hipStream_t stream)
{
  (void)in_sizes; (void)n_in; (void)out_size; (void)d_ws; (void)ws_size;
  const float* targets = (const float*)d_in[0];
  const float* mask    = (const float*)d_in[1];
  const float* wir_w = (const float*)d_in[2];
  const float* wir_b = (const float*)d_in[3];
  const float* whr_w = (const float*)d_in[4];
  const float* whr_b = (const float*)d_in[5];
  const float* wiz_w = (const float*)d_in[6];
  const float* wiz_b = (const float*)d_in[7];
  const float* whz_w = (const float*)d_in[8];
  const float* whz_b = (const float*)d_in[9];
  const float* win_w = (const float*)d_in[10];
  const float* win_b = (const float*)d_in[11];
  const float* whn_w = (const float*)d_in[12];
  const float* whn_b = (const float*)d_in[13];
  const float* wms_w = (const float*)d_in[14];
  const float* wms_b = (const float*)d_in[15];
  const float* w_w   = (const float*)d_in[16];
  const float* w_b   = (const float*)d_in[17];
  const float* wa_w  = (const float*)d_in[18];
  const float* wa_b  = (const float*)d_in[19];
  const float* mu_w  = (const float*)d_in[20];
  const float* mu_b  = (const float*)d_in[21];
  const float* lv_w  = (const float*)d_in[22];
  const float* lv_b  = (const float*)d_in[23];
  float* out = (float*)d_out;

  float* buf;
  hipGetSymbolAddress((void**)&buf, HIP_SYMBOL(g_hid));   // host-side query, graph-capture safe

  // level d=5 with fused leaf children (start=31, 32 nodes -> slots 0..31, S=1)
  level_kernel<true><<<32*B_/TM, NTHR, 0, stream>>>(targets, mask, buf, 1,
      wir_w, wir_b, whr_w, whr_b, wiz_w, wiz_b, whz_w, whz_b,
      win_w, win_b, whn_w, whn_b, wms_w, wms_b, w_w, w_b, wa_w, wa_b, 31);

  // levels d=4..0: S = 2^(5-d); in-place contraction, root lands at slot 0
  for (int d=4; d>=0; --d){
    int S = 1 << (5-d);
    level_kernel<false><<<((1<<d)*B_)/TM, NTHR, 0, stream>>>(targets, mask, buf, S,
        wir_w, wir_b, whr_w, whr_b, wiz_w, wiz_b, whz_w, whz_b,
        win_w, win_b, whn_w, whn_b, wms_w, wms_b, w_w, w_b, wa_w, wa_b,
        (1<<d)-1);
  }

  head_kernel<<<B_/32, 256, 0, stream>>>(buf, mu_w, mu_b, lv_w, lv_b, out);
}

// Round 11
// 11485.519 us; speedup vs baseline: 1.7881x; 1.0013x over previous
//
#include <hip/hip_runtime.h>
#include <hip/hip_bf16.h>

#define B_ 4096
#define H_ 256
#define I_ 32
#define TM 32     // rows per block; wave w owns rows 4w..4w+3, lane owns 4 cols
#define NTHR 512
#define PAD 260

typedef float f4_ __attribute__((ext_vector_type(4)));

// Static inter-level hidden buffer: 32 slots of (B x H) fp32 = 128 MiB.
// In-place binary-tree contraction: level-d node j occupies slot j*2^(5-d).
__device__ float g_hid[(size_t)32 * B_ * H_];

__device__ __forceinline__ float sigf(float x){ return 1.0f/(1.0f+__expf(-x)); }

// ---- GEMM as a macro (named accumulators; no array locals/params).
// acc0..acc3 = X(rows m0..m0+3 of 2D __shared__ XA) @ W(256 x K)^T at cols n0..n0+3.
// Chunk c+1 global-prefetched to named regs after the barrier; ds_write at end.
#define GEMM(WP, XA, K) do{                                                    \
  constexpr int NC=(K)/16;                                                     \
  acc0=(f4_)0.f; acc1=(f4_)0.f; acc2=(f4_)0.f; acc3=(f4_)0.f;                  \
  const float* Wq=(WP);                                                        \
  f4_ p0=*(const f4_*)(Wq+(size_t)na*(K)+4*ja);                                \
  f4_ p1=*(const f4_*)(Wq+(size_t)nb*(K)+4*ja);                                \
  __syncthreads();                    /* prior Wb readers done */              \
  Wb[0][4*ja+0][na]=p0.x; Wb[0][4*ja+1][na]=p0.y;                              \
  Wb[0][4*ja+2][na]=p0.z; Wb[0][4*ja+3][na]=p0.w;                              \
  Wb[0][4*ja+0][nb]=p1.x; Wb[0][4*ja+1][nb]=p1.y;                              \
  Wb[0][4*ja+2][nb]=p1.z; Wb[0][4*ja+3][nb]=p1.w;                              \
  for(int c=0;c<NC;++c){                                                       \
    __syncthreads();                  /* Wb[c&1] visible to all waves */       \
    const int kb=c*16;                                                         \
    if(c+1<NC){                                                                \
      p0=*(const f4_*)(Wq+(size_t)na*(K)+kb+16+4*ja);                          \
      p1=*(const f4_*)(Wq+(size_t)nb*(K)+kb+16+4*ja);                          \
    }                                                                          \
    const int wsel=c&1;                                                        \
    _Pragma("unroll")                                                          \
    for(int ku=0;ku<4;++ku){                                                   \
      f4_ wv0=*(const f4_*)&Wb[wsel][4*ku+0][n0];                              \
      f4_ wv1=*(const f4_*)&Wb[wsel][4*ku+1][n0];                              \
      f4_ wv2=*(const f4_*)&Wb[wsel][4*ku+2][n0];                              \
      f4_ wv3=*(const f4_*)&Wb[wsel][4*ku+3][n0];                              \
      f4_ xv;                                                                  \
      xv=*(const f4_*)&XA[m0+0][kb+4*ku]; acc0+=xv.x*wv0+xv.y*wv1+xv.z*wv2+xv.w*wv3; \
      xv=*(const f4_*)&XA[m0+1][kb+4*ku]; acc1+=xv.x*wv0+xv.y*wv1+xv.z*wv2+xv.w*wv3; \
      xv=*(const f4_*)&XA[m0+2][kb+4*ku]; acc2+=xv.x*wv0+xv.y*wv1+xv.z*wv2+xv.w*wv3; \
      xv=*(const f4_*)&XA[m0+3][kb+4*ku]; acc3+=xv.x*wv0+xv.y*wv1+xv.z*wv2+xv.w*wv3; \
    }                                                                          \
    if(c+1<NC){                                                                \
      const int b2=(c+1)&1;                                                    \
      Wb[b2][4*ja+0][na]=p0.x; Wb[b2][4*ja+1][na]=p0.y;                        \
      Wb[b2][4*ja+2][na]=p0.z; Wb[b2][4*ja+3][na]=p0.w;                        \
      Wb[b2][4*ja+0][nb]=p1.x; Wb[b2][4*ja+1][nb]=p1.y;                        \
      Wb[b2][4*ja+2][nb]=p1.z; Wb[b2][4*ja+3][nb]=p1.w;                        \
    }                                                                          \
  }                                                                            \
}while(0)

#define ROWS(F) F(0) F(1) F(2) F(3)

// ---------------- fused level kernel (in-place slot contraction) ----------------
// amdgpu_waves_per_eu(2,2): pin allocation to 2 waves/EU -> 256-VGPR budget and
// no occupancy reward for squeezing to 128. r5-r9 showed __launch_bounds__'
// min-occupancy hint leaves the backend at 128 VGPR with heavy scratch spill
// (~11 GB writes/dispatch); this attribute sets BOTH min and max.
template<bool FUSE_LEAF>
__global__ __launch_bounds__(NTHR)
__attribute__((amdgpu_waves_per_eu(2,2)))
void level_kernel(const float* __restrict__ targets, const float* __restrict__ mask,
                  float* __restrict__ buf, int S,    // node j: slot j*S ; children at j*S, j*S+S/2
                  const float* __restrict__ wir_w, const float* __restrict__ wir_b,
                  const float* __restrict__ whr_w, const float* __restrict__ whr_b,
                  const float* __restrict__ wiz_w, const float* __restrict__ wiz_b,
                  const float* __restrict__ whz_w, const float* __restrict__ whz_b,
                  const float* __restrict__ win_w, const float* __restrict__ win_b,
                  const float* __restrict__ whn_w, const float* __restrict__ whn_b,
                  const float* __restrict__ wms_w, const float* __restrict__ wms_b,
                  const float* __restrict__ w_w,  const float* __restrict__ w_b,
                  const float* __restrict__ wa_w, const float* __restrict__ wa_b,
                  int start)
{
  __shared__ float Xs[TM][PAD];      // rotating X: c0 -> c1 -> g -> s -> cs (rows wave-private)
  __shared__ float Wb[2][16][PAD];   // double-buffered weight k-chunks [k][n]
  __shared__ float xsm[TM][I_];      // parent x
  __shared__ float xbuf[TM][I_];     // leaf-child x scratch

  const int tid=threadIdx.x;
  const int w=tid>>6, lane=tid&63;
  const int m0=w*4, n0=lane*4;
  const int na=tid>>2, ja=tid&3, nb=128+(tid>>2);   // W staging map (jb==ja)
  const long gr0=(long)blockIdx.x*TM;
  const int node=(int)(gr0/B_), b0=(int)(gr0%B_);
  const size_t slot=(size_t)node*S*B_*H_;
  float* hout=buf+slot+(size_t)b0*H_;
  const int xrow=m0+((lane&31)>>3), xq=4*(lane&7);  // wave-private x map (lanes 0..31)

  if (lane<32){
    const float* xg=targets+((size_t)(start+node)*B_+b0)*I_;
    *(f4_*)&xsm[xrow][xq]=__builtin_nontemporal_load((const f4_*)(xg+(size_t)xrow*I_+xq));
  }

  f4_ acc0,acc1,acc2,acc3;
  f4_ rc00,rc01,rc02,rc03;
  f4_ ss0,ss1,ss2,ss3;            // ss; later reused as xz
  f4_ xr0,xr1,xr2,xr3;            // xr; later reused as xn
  f4_ cs0,cs1,cs2,cs3, nn0,nn1,nn2,nn3;
  float s00,s01,s02,s03, s10,s11,s12,s13;

  // ---- child 0 -> Xs + rc0 ----
  if (FUSE_LEAF){
    if (lane<32){
      const float* x0g=targets+((size_t)(63+2*node)*B_+b0)*I_;
      *(f4_*)&xbuf[xrow][xq]=__builtin_nontemporal_load((const f4_*)(x0g+(size_t)xrow*I_+xq));
    }
    GEMM(wiz_w, xbuf, I_);
    f4_ za0=acc0, za1=acc1, za2=acc2, za3=acc3;
    GEMM(win_w, xbuf, I_);
    f4_ bzs=*(const f4_*)(wiz_b+n0)+*(const f4_*)(whz_b+n0);
    f4_ bns=*(const f4_*)(win_b+n0)+*(const f4_*)(whn_b+n0);
    const float* mkp=mask+(size_t)(63+2*node)*B_+b0;
#define LEAF0(r) { float hm=mkp[m0+r]; f4_ v;                                   \
    v[0]=(1.f-sigf(za##r[0]+bzs[0]))*tanhf(acc##r[0]+bns[0])*hm;                \
    v[1]=(1.f-sigf(za##r[1]+bzs[1]))*tanhf(acc##r[1]+bns[1])*hm;                \
    v[2]=(1.f-sigf(za##r[2]+bzs[2]))*tanhf(acc##r[2]+bns[2])*hm;                \
    v[3]=(1.f-sigf(za##r[3]+bzs[3]))*tanhf(acc##r[3]+bns[3])*hm;                \
    rc0##r=v; *(f4_*)&Xs[m0+r][n0]=v; }
    ROWS(LEAF0)
  } else {
    const float* c0g=buf+slot+(size_t)b0*H_;
#define LD0(r) { f4_ v=__builtin_nontemporal_load((const f4_*)(c0g+(size_t)(m0+r)*H_+n0)); \
    rc0##r=v; *(f4_*)&Xs[m0+r][n0]=v; }
    ROWS(LD0)
  }

  // ---- ms0 -> s0 ----
  GEMM(wms_w, Xs, H_);
  {
    f4_ bm=*(const f4_*)(wms_b+n0), ww=*(const f4_*)(w_w+n0);
    float wb0=w_b[0];
#define MS(r, sdst) { float p=tanhf(acc##r[0]+bm[0])*ww[0]+tanhf(acc##r[1]+bm[1])*ww[1] \
                             +tanhf(acc##r[2]+bm[2])*ww[2]+tanhf(acc##r[3]+bm[3])*ww[3]; \
    p+=__shfl_xor(p,32); p+=__shfl_xor(p,16); p+=__shfl_xor(p,8);               \
    p+=__shfl_xor(p,4);  p+=__shfl_xor(p,2);  p+=__shfl_xor(p,1);               \
    sdst=p+wb0; }
    MS(0,s00) MS(1,s01) MS(2,s02) MS(3,s03)
  }

  // ---- xr ----
  GEMM(wir_w, xsm, I_);
  { f4_ bv=*(const f4_*)(wir_b+n0); xr0=acc0+bv; xr1=acc1+bv; xr2=acc2+bv; xr3=acc3+bv; }

  // ---- r0 ; ss = r0*c0 ----
  GEMM(whr_w, Xs, H_);
  {
    f4_ bv=*(const f4_*)(whr_b+n0);
#define R0(r) { f4_ rv;                                                         \
    rv[0]=sigf(acc##r[0]+xr##r[0]+bv[0]); rv[1]=sigf(acc##r[1]+xr##r[1]+bv[1]); \
    rv[2]=sigf(acc##r[2]+xr##r[2]+bv[2]); rv[3]=sigf(acc##r[3]+xr##r[3]+bv[3]); \
    ss##r=rv*rc0##r; }
    ROWS(R0)
  }

  // ---- child 1 -> Xs (rows wave-private; in-wave read-before-write is safe) ----
  if (FUSE_LEAF){
    if (lane<32){
      const float* x1g=targets+((size_t)(64+2*node)*B_+b0)*I_;
      *(f4_*)&xbuf[xrow][xq]=__builtin_nontemporal_load((const f4_*)(x1g+(size_t)xrow*I_+xq));
    }
    GEMM(wiz_w, xbuf, I_);
    f4_ za0=acc0, za1=acc1, za2=acc2, za3=acc3;
    GEMM(win_w, xbuf, I_);
    f4_ bzs=*(const f4_*)(wiz_b+n0)+*(const f4_*)(whz_b+n0);
    f4_ bns=*(const f4_*)(win_b+n0)+*(const f4_*)(whn_b+n0);
    const float* mkp=mask+(size_t)(64+2*node)*B_+b0;
#define LEAF1(r) { float hm=mkp[m0+r]; f4_ v;                                   \
    v[0]=(1.f-sigf(za##r[0]+bzs[0]))*tanhf(acc##r[0]+bns[0])*hm;                \
    v[1]=(1.f-sigf(za##r[1]+bzs[1]))*tanhf(acc##r[1]+bns[1])*hm;                \
    v[2]=(1.f-sigf(za##r[2]+bzs[2]))*tanhf(acc##r[2]+bns[2])*hm;                \
    v[3]=(1.f-sigf(za##r[3]+bzs[3]))*tanhf(acc##r[3]+bns[3])*hm;                \
    *(f4_*)&Xs[m0+r][n0]=v; }
    ROWS(LEAF1)
  } else {
    const float* c1g=buf+slot+(size_t)(S>>1)*B_*H_+(size_t)b0*H_;
#define LD1(r) { f4_ v=__builtin_nontemporal_load((const f4_*)(c1g+(size_t)(m0+r)*H_+n0)); \
    *(f4_*)&Xs[m0+r][n0]=v; }
    ROWS(LD1)
  }

  // ---- ms1 -> s1 ----
  GEMM(wms_w+H_*H_, Xs, H_);
  {
    f4_ bm=*(const f4_*)(wms_b+H_+n0), ww=*(const f4_*)(w_w+n0);
    float wb0=w_b[0];
    MS(0,s10) MS(1,s11) MS(2,s12) MS(3,s13)
  }

  // ---- r1 ; ss += r1*c1 ; g = a0*c0 + a1*c1 -> Xs ----
  GEMM(whr_w, Xs, H_);
  {
    f4_ bv=*(const f4_*)(whr_b+n0);
#define R1(r, sA, sB) { f4_ c1t=*(const f4_*)&Xs[m0+r][n0]; f4_ rv;             \
    rv[0]=sigf(acc##r[0]+xr##r[0]+bv[0]); rv[1]=sigf(acc##r[1]+xr##r[1]+bv[1]); \
    rv[2]=sigf(acc##r[2]+xr##r[2]+bv[2]); rv[3]=sigf(acc##r[3]+xr##r[3]+bv[3]); \
    ss##r+=rv*c1t; float sum=sA+sB; float a0v=sA/sum, a1v=sB/sum;               \
    *(f4_*)&Xs[m0+r][n0]=a0v*rc0##r+a1v*c1t; }
    R1(0,s00,s10) R1(1,s01,s11) R1(2,s02,s12) R1(3,s03,s13)
  }

  // ---- child_sum = tanh(g@wa^T + b) ; then Xs <- ss ----
  GEMM(wa_w, Xs, H_);
  {
    f4_ bv=*(const f4_*)(wa_b+n0);
#define CSX(r) { f4_ v;                                                         \
    v[0]=tanhf(acc##r[0]+bv[0]); v[1]=tanhf(acc##r[1]+bv[1]);                   \
    v[2]=tanhf(acc##r[2]+bv[2]); v[3]=tanhf(acc##r[3]+bv[3]);                   \
    cs##r=v; *(f4_*)&Xs[m0+r][n0]=ss##r; }
    ROWS(CSX)
  }

  // ---- xn (reuses xr regs) ; n = tanh(xn + s@whn^T + b) ; then Xs <- cs ----
  GEMM(win_w, xsm, I_);
  { f4_ bv=*(const f4_*)(win_b+n0); xr0=acc0+bv; xr1=acc1+bv; xr2=acc2+bv; xr3=acc3+bv; }
  GEMM(whn_w, Xs, H_);
  {
    f4_ bv=*(const f4_*)(whn_b+n0);
#define NNX(r) { f4_ v;                                                         \
    v[0]=tanhf(acc##r[0]+xr##r[0]+bv[0]); v[1]=tanhf(acc##r[1]+xr##r[1]+bv[1]); \
    v[2]=tanhf(acc##r[2]+xr##r[2]+bv[2]); v[3]=tanhf(acc##r[3]+xr##r[3]+bv[3]); \
    nn##r=v; *(f4_*)&Xs[m0+r][n0]=cs##r; }
    ROWS(NNX)
  }

  // ---- xz (reuses ss regs) ; z ; h = (1-z)*n + z*cs ; store h*mask ----
  GEMM(wiz_w, xsm, I_);
  { f4_ bv=*(const f4_*)(wiz_b+n0); ss0=acc0+bv; ss1=acc1+bv; ss2=acc2+bv; ss3=acc3+bv; }
  GEMM(whz_w, Xs, H_);
  {
    f4_ bv=*(const f4_*)(whz_b+n0);
    const float* mkp=mask+(size_t)(start+node)*B_+b0;
#define HZ(r) { float hm=mkp[m0+r]; f4_ o; float z;                             \
    z=sigf(acc##r[0]+ss##r[0]+bv[0]); o[0]=((1.f-z)*nn##r[0]+z*cs##r[0])*hm;    \
    z=sigf(acc##r[1]+ss##r[1]+bv[1]); o[1]=((1.f-z)*nn##r[1]+z*cs##r[1])*hm;    \
    z=sigf(acc##r[2]+ss##r[2]+bv[2]); o[2]=((1.f-z)*nn##r[2]+z*cs##r[2])*hm;    \
    z=sigf(acc##r[3]+ss##r[3]+bv[3]); o[3]=((1.f-z)*nn##r[3]+z*cs##r[3])*hm;    \
    __builtin_nontemporal_store(o,(f4_*)(hout+(size_t)(m0+r)*H_+n0)); }
    ROWS(HZ)
  }
}

// ---------------- output heads: mu = root@mu_w^T+mu_b ; lv = root@lv_w^T+lv_b
__global__ __launch_bounds__(256)
void head_kernel(const float* __restrict__ root,
                 const float* __restrict__ mu_w, const float* __restrict__ mu_b,
                 const float* __restrict__ lv_w, const float* __restrict__ lv_b,
                 float* __restrict__ out)
{
  __shared__ float rs[32][260];
  const int tid = threadIdx.x;
  const int r0 = blockIdx.x*32;
#pragma unroll
  for (int i=0;i<8;++i){
    int q = i*256+tid;
    int m=q>>6, kq=q&63;
    *(float4*)&rs[m][4*kq] = *(const float4*)(root + (size_t)(r0+m)*H_ + 4*kq);
  }
  __syncthreads();
  const float* W; float bias; float* ob;
  if (tid<128){ W = mu_w + tid*H_; bias = mu_b[tid]; ob = out + tid; }
  else        { W = lv_w + (tid-128)*H_; bias = lv_b[tid-128]; ob = out + (size_t)B_*128 + (tid-128); }
  float acc[32];
#pragma unroll
  for (int m=0;m<32;++m) acc[m]=0.f;
  for (int k0=0;k0<H_;k0+=8){
    float4 w0=*(const float4*)(W+k0), w1=*(const float4*)(W+k0+4);
#pragma unroll
    for (int m=0;m<32;++m){
      float4 x0=*(const float4*)&rs[m][k0], x1=*(const float4*)&rs[m][k0+4];
      acc[m] += x0.x*w0.x + x0.y*w0.y + x0.z*w0.z + x0.w*w0.w
              + x1.x*w1.x + x1.y*w1.y + x1.z*w1.z + x1.w*w1.w;
    }
  }
#pragma unroll
  for (int m=0;m<32;++m) ob[(size_t)(r0+m)*128] = acc[m] + bias;
}

extern "C" void kernel_launch(void* const* d_in, const int* in_sizes, int n_in,
                              void* d_out, int out_size, void* d_ws, size_t ws_size,
                              hipStream_t stream)
{
  (void)in_sizes; (void)n_in; (void)out_size; (void)d_ws; (void)ws_size;
  const float* targets = (const float*)d_in[0];
  const float* mask    = (const float*)d_in[1];
  const float* wir_w = (const float*)d_in[2];
  const float* wir_b = (const float*)d_in[3];
  const float* whr_w = (const float*)d_in[4];
  const float* whr_b = (const float*)d_in[5];
  const float* wiz_w = (const float*)d_in[6];
  const float* wiz_b = (const float*)d_in[7];
  const float* whz_w = (const float*)d_in[8];
  const float* whz_b = (const float*)d_in[9];
  const float* win_w = (const float*)d_in[10];
  const float* win_b = (const float*)d_in[11];
  const float* whn_w = (const float*)d_in[12];
  const float* whn_b = (const float*)d_in[13];
  const float* wms_w = (const float*)d_in[14];
  const float* wms_b = (const float*)d_in[15];
  const float* w_w   = (const float*)d_in[16];
  const float* w_b   = (const float*)d_in[17];
  const float* wa_w  = (const float*)d_in[18];
  const float* wa_b  = (const float*)d_in[19];
  const float* mu_w  = (const float*)d_in[20];
  const float* mu_b  = (const float*)d_in[21];
  const float* lv_w  = (const float*)d_in[22];
  const float* lv_b  = (const float*)d_in[23];
  float* out = (float*)d_out;

  float* buf;
  hipGetSymbolAddress((void**)&buf, HIP_SYMBOL(g_hid));   // host-side query, graph-capture safe

  // level d=5 with fused leaf children (start=31, 32 nodes -> slots 0..31, S=1)
  level_kernel<true><<<32*B_/TM, NTHR, 0, stream>>>(targets, mask, buf, 1,
      wir_w, wir_b, whr_w, whr_b, wiz_w, wiz_b, whz_w, whz_b,
      win_w, win_b, whn_w, whn_b, wms_w, wms_b, w_w, w_b, wa_w, wa_b, 31);

  // levels d=4..0: S = 2^(5-d); in-place contraction, root lands at slot 0
  for (int d=4; d>=0; --d){
    int S = 1 << (5-d);
    level_kernel<false><<<((1<<d)*B_)/TM, NTHR, 0, stream>>>(targets, mask, buf, S,
        wir_w, wir_b, whr_w, whr_b, wiz_w, wiz_b, whz_w, whz_b,
        win_w, win_b, whn_w, whn_b, wms_w, wms_b, w_w, w_b, wa_w, wa_b,
        (1<<d)-1);
  }

  head_kernel<<<B_/32, 256, 0, stream>>>(buf, mu_w, mu_b, lv_w, lv_b, out);
}